// Round 2
// baseline (1888.942 us; speedup 1.0000x reference)
//
#include <hip/hip_runtime.h>
#include <hip/hip_bf16.h>
#include <cstdint>

static constexpr int NS_N = 50000;
static constexpr int ND_N = 50000;
static constexpr int E_N  = 500000;

__device__ __forceinline__ float sigm(float x) { return 1.f / (1.f + __expf(-x)); }

// ---------------- CSR build ----------------
__global__ void count_kernel(const int* __restrict__ dst, int* __restrict__ cnt, int n) {
  int i = blockIdx.x * blockDim.x + threadIdx.x;
  if (i < n) atomicAdd(&cnt[dst[i]], 1);
}

__global__ void fill_kernel(const int* __restrict__ src, const int* __restrict__ dst,
                            const int* __restrict__ row_ptr, int* __restrict__ fil,
                            int* __restrict__ csr_src, int n) {
  int i = blockIdx.x * blockDim.x + threadIdx.x;
  if (i < n) {
    int d = dst[i];
    int pos = row_ptr[d] + atomicAdd(&fil[d], 1);
    csr_src[pos] = src[i];
  }
}

// single-block exclusive scan over n ints, also writes out[n] = total
__global__ __launch_bounds__(1024) void exscan_kernel(const int* __restrict__ in,
                                                      int* __restrict__ out, int n) {
  __shared__ int wsum[16];
  __shared__ int carry_s;
  const int tid = threadIdx.x;
  const int lane = tid & 63;
  const int w = tid >> 6;
  if (tid == 0) carry_s = 0;
  for (int base = 0; base < n; base += 1024) {
    int i = base + tid;
    int x = (i < n) ? in[i] : 0;
    int v = x;
    #pragma unroll
    for (int off = 1; off < 64; off <<= 1) {
      int t = __shfl_up(v, off);
      if (lane >= off) v += t;
    }
    if (lane == 63) wsum[w] = v;
    __syncthreads();                       // (A)
    if (tid == 0) {
      int run = 0;
      #pragma unroll
      for (int k = 0; k < 16; ++k) { run += wsum[k]; wsum[k] = run; }
    }
    __syncthreads();                       // (B)
    int woff = (w == 0) ? 0 : wsum[w - 1];
    if (i < n) out[i] = carry_s + woff + v - x;
    int total = wsum[15];
    __syncthreads();                       // (C)
    if (tid == 0) carry_s += total;
  }
  __syncthreads();
  if (tid == 0) out[n] = carry_s;
}

// ---------------- generic dense: out = act(in @ W^T + b), all f32 ----------------
template<int IN, int OUTD, int NPB, bool RELU>
__global__ __launch_bounds__(256) void dense_kernel(
    const float* __restrict__ in_, const float* __restrict__ W,
    const float* __restrict__ b, float* __restrict__ out_, int N)
{
  static_assert(256 % OUTD == 0 && IN % 2 == 0 && NPB % (256 / OUTD) == 0, "");
  constexpr int P = 256 / OUTD;
  constexpr int IN2 = IN / 2;
  constexpr int NPT = NPB / P;
  constexpr int WPITCH = OUTD + 1;          // pad to break LDS write conflicts
  __shared__ float2 Wt[IN2 * WPITCH];       // transposed [m][j]
  __shared__ float xl[NPB][IN];
  const int tid = threadIdx.x;
  const float2* W2 = (const float2*)W;
  for (int idx = tid; idx < IN2 * OUTD; idx += 256) {
    int j = idx / IN2, m = idx % IN2;
    Wt[m * WPITCH + j] = W2[j * IN2 + m];
  }
  const int nb = blockIdx.x * NPB;
  for (int idx = tid; idx < NPB * IN; idx += 256) {
    int n = idx / IN, k = idx % IN;
    xl[n][k] = (nb + n < N) ? in_[(size_t)(nb + n) * IN + k] : 0.f;
  }
  __syncthreads();
  const int j = tid % OUTD;
  const int slot = tid / OUTD;
  const float bj = b[j];
  float acc[NPT];
  #pragma unroll
  for (int t = 0; t < NPT; ++t) acc[t] = bj;
  #pragma unroll
  for (int m = 0; m < IN2; ++m) {
    const float2 wv = Wt[m * WPITCH + j];
    #pragma unroll
    for (int t = 0; t < NPT; ++t) {
      const float2 x = ((const float2*)(&xl[slot + t * P][0]))[m];
      acc[t] += x.x * wv.x;
      acc[t] += x.y * wv.y;
    }
  }
  #pragma unroll
  for (int t = 0; t < NPT; ++t) {
    int n = nb + slot + t * P;
    if (n < N) {
      float v = acc[t];
      if constexpr (RELU) v = fmaxf(v, 0.f);
      out_[(size_t)n * OUTD + j] = v;
    }
  }
}

// ---------------- stream encoder: LSTM(1 step) + concat + dense 48->128 ----------------
__global__ __launch_bounds__(256) void enc_stream_kernel(
    const float* __restrict__ xs,   // NS x 17
    const float* __restrict__ W_ih, // 128 x 1
    const float* __restrict__ b_ih,
    const float* __restrict__ b_hh,
    const float* __restrict__ scW,  // 128 x 48
    const float* __restrict__ scb,
    float* __restrict__ out, int N)
{
  constexpr int IN = 48, OUTD = 128, NPB = 8, IN2 = 24, NPT = 4;
  constexpr int WPITCH = OUTD + 1;
  __shared__ float2 Wt[IN2 * WPITCH];
  __shared__ float xl[NPB][IN];
  const int tid = threadIdx.x;
  const float2* W2 = (const float2*)scW;
  for (int idx = tid; idx < IN2 * OUTD; idx += 256) {
    int j = idx / IN2, m = idx % IN2;
    Wt[m * WPITCH + j] = W2[j * IN2 + m];
  }
  const int nb = blockIdx.x * NPB;
  for (int idx = tid; idx < NPB * 16; idx += 256) {
    int n = idx >> 4, f = idx & 15;
    xl[n][f] = (nb + n < N) ? xs[(size_t)(nb + n) * 17 + f] : 0.f;
  }
  {
    int n = tid >> 5, jj = tid & 31;
    float h = 0.f;
    if (nb + n < N) {
      float xr = xs[(size_t)(nb + n) * 17 + 16];
      float gi = xr * W_ih[jj]      + b_ih[jj]      + b_hh[jj];
      float gg = xr * W_ih[64 + jj] + b_ih[64 + jj] + b_hh[64 + jj];
      float go = xr * W_ih[96 + jj] + b_ih[96 + jj] + b_hh[96 + jj];
      float c = sigm(gi) * tanhf(gg);
      h = sigm(go) * tanhf(c);
    }
    xl[n][16 + jj] = h;
  }
  __syncthreads();
  const int j = tid & 127;
  const int slot = tid >> 7;
  const float bj = scb[j];
  float acc[NPT];
  #pragma unroll
  for (int t = 0; t < NPT; ++t) acc[t] = bj;
  #pragma unroll
  for (int m = 0; m < IN2; ++m) {
    const float2 wv = Wt[m * WPITCH + j];
    #pragma unroll
    for (int t = 0; t < NPT; ++t) {
      const float2 x = ((const float2*)(&xl[slot + t * 2][0]))[m];
      acc[t] += x.x * wv.x;
      acc[t] += x.y * wv.y;
    }
  }
  #pragma unroll
  for (int t = 0; t < NPT; ++t) {
    int n = nb + slot + t * 2;
    if (n < N) out[(size_t)n * 128 + j] = fmaxf(acc[t], 0.f);
  }
}

// ---------------- per-node attention scores (two roles fused) ----------------
__global__ void a_scores_kernel(const float* __restrict__ xs,
                                const float* __restrict__ attA,
                                const float* __restrict__ attB,
                                float* __restrict__ outA, float* __restrict__ outB, int n) {
  int idx = blockIdx.x * blockDim.x + threadIdx.x;
  if (idx >= n * 8) return;
  int node = idx >> 3, h = idx & 7;
  const float4* xp = (const float4*)(xs + (size_t)node * 128 + h * 16);
  float sa = 0.f, sb = 0.f;
  #pragma unroll
  for (int q4 = 0; q4 < 4; ++q4) {
    float4 x = xp[q4];
    int base = h * 16 + q4 * 4;
    sa += x.x * attA[base + 0]; sb += x.x * attB[base + 0];
    sa += x.y * attA[base + 1]; sb += x.y * attB[base + 1];
    sa += x.z * attA[base + 2]; sb += x.z * attB[base + 2];
    sa += x.w * attA[base + 3]; sb += x.w * attB[base + 3];
  }
  outA[idx] = sa; outB[idx] = sb;
}

// ---------------- fused segment-softmax + aggregation, one wave per dst ----------------
#define AGG_CAP 64
__global__ __launch_bounds__(256) void att_agg_kernel(
    const int* __restrict__ row_ptr, const int* __restrict__ csr_src,
    const float* __restrict__ a_src, const float* __restrict__ a_dst,
    const float* __restrict__ xs_src, float* __restrict__ h_out, int n_dst)
{
  __shared__ float wexp[4][AGG_CAP][8];
  const int lane = threadIdx.x & 63;
  const int w = threadIdx.x >> 6;
  const int dst = blockIdx.x * 4 + w;
  if (dst >= n_dst) return;
  const int start = row_ptr[dst];
  const int deg = row_ptr[dst + 1] - start;
  float ad[8];
  {
    const float4* p = (const float4*)(a_dst + (size_t)dst * 8);
    float4 a0 = p[0], a1 = p[1];
    ad[0]=a0.x; ad[1]=a0.y; ad[2]=a0.z; ad[3]=a0.w;
    ad[4]=a1.x; ad[5]=a1.y; ad[6]=a1.z; ad[7]=a1.w;
  }
  float mh[8];
  #pragma unroll
  for (int h = 0; h < 8; ++h) mh[h] = -3.0e38f;
  // pass 1: leaky-relu logits + per-head max (cache logits in LDS)
  for (int jj = lane; jj < deg; jj += 64) {
    int s = csr_src[start + jj];
    const float4* p = (const float4*)(a_src + (size_t)s * 8);
    float4 a0 = p[0], a1 = p[1];
    float lg[8] = {a0.x+ad[0], a0.y+ad[1], a0.z+ad[2], a0.w+ad[3],
                   a1.x+ad[4], a1.y+ad[5], a1.z+ad[6], a1.w+ad[7]};
    #pragma unroll
    for (int h = 0; h < 8; ++h) {
      float v = lg[h];
      v = (v >= 0.f) ? v : 0.2f * v;
      if (jj < AGG_CAP) wexp[w][jj][h] = v;
      mh[h] = fmaxf(mh[h], v);
    }
  }
  #pragma unroll
  for (int off = 32; off; off >>= 1)
    #pragma unroll
    for (int h = 0; h < 8; ++h) mh[h] = fmaxf(mh[h], __shfl_xor(mh[h], off));
  // pass 2: exp + per-head sum
  float sh[8] = {0,0,0,0,0,0,0,0};
  for (int jj = lane; jj < deg; jj += 64) {
    float lg[8];
    if (jj < AGG_CAP) {
      #pragma unroll
      for (int h = 0; h < 8; ++h) lg[h] = wexp[w][jj][h];
    } else {
      int s = csr_src[start + jj];
      const float4* p = (const float4*)(a_src + (size_t)s * 8);
      float4 a0 = p[0], a1 = p[1];
      float t[8] = {a0.x+ad[0], a0.y+ad[1], a0.z+ad[2], a0.w+ad[3],
                    a1.x+ad[4], a1.y+ad[5], a1.z+ad[6], a1.w+ad[7]};
      #pragma unroll
      for (int h = 0; h < 8; ++h) { float v = t[h]; lg[h] = (v >= 0.f) ? v : 0.2f * v; }
    }
    #pragma unroll
    for (int h = 0; h < 8; ++h) {
      float e = __expf(lg[h] - mh[h]);
      if (jj < AGG_CAP) wexp[w][jj][h] = e;
      sh[h] += e;
    }
  }
  #pragma unroll
  for (int off = 32; off; off >>= 1)
    #pragma unroll
    for (int h = 0; h < 8; ++h) sh[h] += __shfl_xor(sh[h], off);
  float inv[8];
  #pragma unroll
  for (int h = 0; h < 8; ++h) inv[h] = 1.f / (sh[h] + 1e-16f);
  // pass 3: dim-parallel weighted aggregation
  const int d0 = lane, d1 = lane + 64;
  const int h0 = lane >> 4, h1 = 4 + (lane >> 4);
  float acc0 = 0.f, acc1 = 0.f;
  for (int jj = 0; jj < deg; ++jj) {
    int s = csr_src[start + jj];
    float w0, w1;
    if (jj < AGG_CAP) {
      w0 = wexp[w][jj][h0] * inv[h0];
      w1 = wexp[w][jj][h1] * inv[h1];
    } else {
      float v0 = a_src[(size_t)s * 8 + h0] + ad[h0];
      v0 = (v0 >= 0.f) ? v0 : 0.2f * v0;
      w0 = __expf(v0 - mh[h0]) * inv[h0];
      float v1 = a_src[(size_t)s * 8 + h1] + ad[h1];
      v1 = (v1 >= 0.f) ? v1 : 0.2f * v1;
      w1 = __expf(v1 - mh[h1]) * inv[h1];
    }
    const float* xr = xs_src + (size_t)s * 128;
    acc0 += w0 * xr[d0];
    acc1 += w1 * xr[d1];
  }
  h_out[(size_t)dst * 128 + d0] = fmaxf(acc0, 0.f);
  h_out[(size_t)dst * 128 + d1] = fmaxf(acc1, 0.f);
}

// ---------------- launch ----------------
extern "C" void kernel_launch(void* const* d_in, const int* in_sizes, int n_in,
                              void* d_out, int out_size, void* d_ws, size_t ws_size,
                              hipStream_t stream) {
  (void)in_sizes; (void)n_in; (void)out_size; (void)ws_size;
  const float* x_stream  = (const float*)d_in[0];
  const float* x_device  = (const float*)d_in[1];
  const int*   edge_sd   = (const int*)d_in[2];
  const int*   edge_ds   = (const int*)d_in[3];
  const float* lstm_W_ih = (const float*)d_in[4];
  const float* lstm_b_ih = (const float*)d_in[5];
  const float* lstm_b_hh = (const float*)d_in[6];
  const float* sc_W      = (const float*)d_in[7];
  const float* sc_b      = (const float*)d_in[8];
  const float* dev_W     = (const float*)d_in[9];
  const float* dev_b     = (const float*)d_in[10];
  const float* proj_W    = (const float*)d_in[11];
  const float* proj_b    = (const float*)d_in[12];
  const float* att_src   = (const float*)d_in[13];
  const float* att_dst   = (const float*)d_in[14];
  // d_in[15..17] = q, k_W, k_b — mathematically unused (softmax over singleton stack)
  const float* outp_W1   = (const float*)d_in[18];
  const float* outp_b1   = (const float*)d_in[19];
  const float* outp_W2   = (const float*)d_in[20];
  const float* outp_b2   = (const float*)d_in[21];
  float* out_f = (float*)d_out;

  float* ws = (float*)d_ws;
  size_t off = 0;
  float* h0  = ws + off; off += (size_t)NS_N * 128;
  float* h1  = ws + off; off += (size_t)ND_N * 128;
  float* xs0 = ws + off; off += (size_t)NS_N * 128;
  float* xs1 = ws + off; off += (size_t)ND_N * 128;
  float* as0 = ws + off; off += (size_t)NS_N * 8;
  float* ad0 = ws + off; off += (size_t)NS_N * 8;
  float* as1 = ws + off; off += (size_t)ND_N * 8;
  float* ad1 = ws + off; off += (size_t)ND_N * 8;
  int* ip = (int*)(ws + off);
  int* rp_sd  = ip; ip += ND_N + 1;
  int* rp_ds  = ip; ip += NS_N + 1;
  int* csr_sd = ip; ip += E_N;
  int* csr_ds = ip; ip += E_N;
  int* cnt    = ip; ip += (NS_N > ND_N ? NS_N : ND_N);
  int* fil    = ip;

  const int EB = (E_N + 255) / 256;
  // CSR for edge_sd (dst = device nodes)
  hipMemsetAsync(cnt, 0, ND_N * sizeof(int), stream);
  count_kernel<<<EB, 256, 0, stream>>>(edge_sd + E_N, cnt, E_N);
  exscan_kernel<<<1, 1024, 0, stream>>>(cnt, rp_sd, ND_N);
  hipMemsetAsync(fil, 0, ND_N * sizeof(int), stream);
  fill_kernel<<<EB, 256, 0, stream>>>(edge_sd, edge_sd + E_N, rp_sd, fil, csr_sd, E_N);
  // CSR for edge_ds (dst = stream nodes)
  hipMemsetAsync(cnt, 0, NS_N * sizeof(int), stream);
  count_kernel<<<EB, 256, 0, stream>>>(edge_ds + E_N, cnt, E_N);
  exscan_kernel<<<1, 1024, 0, stream>>>(cnt, rp_ds, NS_N);
  hipMemsetAsync(fil, 0, NS_N * sizeof(int), stream);
  fill_kernel<<<EB, 256, 0, stream>>>(edge_ds, edge_ds + E_N, rp_ds, fil, csr_ds, E_N);

  // encoders
  enc_stream_kernel<<<(NS_N + 7) / 8, 256, 0, stream>>>(
      x_stream, lstm_W_ih, lstm_b_ih, lstm_b_hh, sc_W, sc_b, h0, NS_N);
  dense_kernel<32, 128, 8, true><<<(ND_N + 7) / 8, 256, 0, stream>>>(
      x_device, dev_W, dev_b, h1, ND_N);

  // GNN layers
  for (int l = 0; l < 2; ++l) {
    dense_kernel<128, 128, 8, false><<<(NS_N + 7) / 8, 256, 0, stream>>>(
        h0, proj_W + (size_t)(l * 2 + 0) * 16384, proj_b + (l * 2 + 0) * 128, xs0, NS_N);
    dense_kernel<128, 128, 8, false><<<(ND_N + 7) / 8, 256, 0, stream>>>(
        h1, proj_W + (size_t)(l * 2 + 1) * 16384, proj_b + (l * 2 + 1) * 128, xs1, ND_N);
    // type0 nodes: src-role in e=0 (att_src[l,0]); dst-role in e=1 (att_dst[l,1])
    a_scores_kernel<<<(NS_N * 8 + 255) / 256, 256, 0, stream>>>(
        xs0, att_src + (l * 2 + 0) * 128, att_dst + (l * 2 + 1) * 128, as0, ad0, NS_N);
    // type1 nodes: src-role in e=1 (att_src[l,1]); dst-role in e=0 (att_dst[l,0])
    a_scores_kernel<<<(ND_N * 8 + 255) / 256, 256, 0, stream>>>(
        xs1, att_src + (l * 2 + 1) * 128, att_dst + (l * 2 + 0) * 128, as1, ad1, ND_N);
    // e=0: stream -> device, writes new h1
    att_agg_kernel<<<(ND_N + 3) / 4, 256, 0, stream>>>(rp_sd, csr_sd, as0, ad1, xs0, h1, ND_N);
    // e=1: device -> stream, writes new h0
    att_agg_kernel<<<(NS_N + 3) / 4, 256, 0, stream>>>(rp_ds, csr_ds, as1, ad0, xs1, h0, NS_N);
  }

  // output heads (xs0/xs1 reused as temps)
  dense_kernel<128, 64, 8, true><<<(NS_N + 7) / 8, 256, 0, stream>>>(
      h0, outp_W1, outp_b1, xs0, NS_N);
  dense_kernel<64, 64, 8, false><<<(NS_N + 7) / 8, 256, 0, stream>>>(
      xs0, outp_W2, outp_b2, out_f, NS_N);
  dense_kernel<128, 64, 8, true><<<(ND_N + 7) / 8, 256, 0, stream>>>(
      h1, outp_W1 + 64 * 128, outp_b1 + 64, xs1, ND_N);
  dense_kernel<64, 64, 8, false><<<(ND_N + 7) / 8, 256, 0, stream>>>(
      xs1, outp_W2 + 64 * 64, outp_b2 + 64, out_f + (size_t)NS_N * 64, ND_N);
}

// Round 3
// 1026.092 us; speedup vs baseline: 1.8409x; 1.8409x over previous
//
#include <hip/hip_runtime.h>
#include <hip/hip_bf16.h>
#include <cstdint>

static constexpr int NS_N = 50000;
static constexpr int ND_N = 50000;
static constexpr int E_N  = 500000;

__device__ __forceinline__ float sigm(float x) { return 1.f / (1.f + __expf(-x)); }

// ---------------- CSR build ----------------
__global__ void count_kernel(const int* __restrict__ dst, int* __restrict__ cnt, int n) {
  int i = blockIdx.x * blockDim.x + threadIdx.x;
  if (i < n) atomicAdd(&cnt[dst[i]], 1);
}

__global__ void fill_kernel(const int* __restrict__ src, const int* __restrict__ dst,
                            const int* __restrict__ row_ptr, int* __restrict__ fil,
                            int* __restrict__ csr_src, int n) {
  int i = blockIdx.x * blockDim.x + threadIdx.x;
  if (i < n) {
    int d = dst[i];
    int pos = row_ptr[d] + atomicAdd(&fil[d], 1);
    csr_src[pos] = src[i];
  }
}

// single-block exclusive scan over n ints, also writes out[n] = total
__global__ __launch_bounds__(1024) void exscan_kernel(const int* __restrict__ in,
                                                      int* __restrict__ out, int n) {
  __shared__ int wsum[16];
  __shared__ int carry_s;
  const int tid = threadIdx.x;
  const int lane = tid & 63;
  const int w = tid >> 6;
  if (tid == 0) carry_s = 0;
  for (int base = 0; base < n; base += 1024) {
    int i = base + tid;
    int x = (i < n) ? in[i] : 0;
    int v = x;
    #pragma unroll
    for (int off = 1; off < 64; off <<= 1) {
      int t = __shfl_up(v, off);
      if (lane >= off) v += t;
    }
    if (lane == 63) wsum[w] = v;
    __syncthreads();
    if (tid == 0) {
      int run = 0;
      #pragma unroll
      for (int k = 0; k < 16; ++k) { run += wsum[k]; wsum[k] = run; }
    }
    __syncthreads();
    int woff = (w == 0) ? 0 : wsum[w - 1];
    if (i < n) out[i] = carry_s + woff + v - x;
    int total = wsum[15];
    __syncthreads();
    if (tid == 0) carry_s += total;
  }
  __syncthreads();
  if (tid == 0) out[n] = carry_s;
}

// ---------------- dense v2: register-tiled f32 GEMM, out = act(in @ W^T + b) ----------------
// Block: 256 threads. BN nodes/block. Thread (colq, nodeg) computes 4 cols x TM nodes.
// W staged TRANSPOSED in LDS: Wl[k*WP + j], WP = M+4 (16B-aligned float4 rows, contiguous
// 512B row sweeps per wave). x staged row-major; x reads are 2-address wave broadcasts (free).
template<int K, int M, int BN, bool RELU>
__global__ __launch_bounds__(256) void dense2_kernel(
    const float* __restrict__ in_, const float* __restrict__ W,
    const float* __restrict__ b, float* __restrict__ out_, int N)
{
  static_assert(M % 4 == 0 && K % 4 == 0, "");
  constexpr int COLG = M / 4;
  constexpr int NODEG = 256 / COLG;
  constexpr int TM = BN / NODEG;
  constexpr int WP = M + 4;
  static_assert(BN % NODEG == 0 && 256 % COLG == 0, "");
  __shared__ float Wl[K * WP];
  __shared__ float xl[BN * K];
  const int tid = threadIdx.x;
  // stage W transposed: Wl[k*WP + j] = W[j*K + k]  (coalesced global reads)
  for (int idx = tid; idx < M * K; idx += 256) {
    int j = idx / K, k = idx % K;
    Wl[k * WP + j] = W[idx];
  }
  const int nb = blockIdx.x * BN;
  for (int idx = tid; idx < BN * K; idx += 256) {
    int n = idx / K;
    xl[idx] = (nb + n < N) ? in_[(size_t)nb * K + idx] : 0.f;
  }
  __syncthreads();
  const int colq = tid % COLG;
  const int nodeg = tid / COLG;
  const float4 bv = *(const float4*)&b[4 * colq];
  float acc[TM][4];
  #pragma unroll
  for (int t = 0; t < TM; ++t) {
    acc[t][0] = bv.x; acc[t][1] = bv.y; acc[t][2] = bv.z; acc[t][3] = bv.w;
  }
  for (int k = 0; k < K; k += 4) {
    const float4 wv0 = *(const float4*)&Wl[(k + 0) * WP + 4 * colq];
    const float4 wv1 = *(const float4*)&Wl[(k + 1) * WP + 4 * colq];
    const float4 wv2 = *(const float4*)&Wl[(k + 2) * WP + 4 * colq];
    const float4 wv3 = *(const float4*)&Wl[(k + 3) * WP + 4 * colq];
    #pragma unroll
    for (int t = 0; t < TM; ++t) {
      const float4 xv = *(const float4*)&xl[(nodeg * TM + t) * K + k];
      acc[t][0] += xv.x * wv0.x + xv.y * wv1.x + xv.z * wv2.x + xv.w * wv3.x;
      acc[t][1] += xv.x * wv0.y + xv.y * wv1.y + xv.z * wv2.y + xv.w * wv3.y;
      acc[t][2] += xv.x * wv0.z + xv.y * wv1.z + xv.z * wv2.z + xv.w * wv3.z;
      acc[t][3] += xv.x * wv0.w + xv.y * wv1.w + xv.z * wv2.w + xv.w * wv3.w;
    }
  }
  #pragma unroll
  for (int t = 0; t < TM; ++t) {
    int n = nb + nodeg * TM + t;
    if (n < N) {
      float4 v = make_float4(acc[t][0], acc[t][1], acc[t][2], acc[t][3]);
      if constexpr (RELU) {
        v.x = fmaxf(v.x, 0.f); v.y = fmaxf(v.y, 0.f);
        v.z = fmaxf(v.z, 0.f); v.w = fmaxf(v.w, 0.f);
      }
      *(float4*)&out_[(size_t)n * M + 4 * colq] = v;
    }
  }
}

// ---------------- stream encoder v2: LSTM(1 step) + concat staged, then dense 48->128 ----------------
__global__ __launch_bounds__(256) void enc_stream2_kernel(
    const float* __restrict__ xs,   // NS x 17
    const float* __restrict__ W_ih, // 128 x 1
    const float* __restrict__ b_ih,
    const float* __restrict__ b_hh,
    const float* __restrict__ scW,  // 128 x 48
    const float* __restrict__ scb,
    float* __restrict__ out, int N)
{
  constexpr int K = 48, M = 128, BN = 128;
  constexpr int COLG = M / 4, NODEG = 256 / COLG, TM = BN / NODEG, WP = M + 4;
  __shared__ float Wl[K * WP];
  __shared__ float xl[BN * K];
  const int tid = threadIdx.x;
  for (int idx = tid; idx < M * K; idx += 256) {
    int j = idx / K, k = idx % K;
    Wl[k * WP + j] = scW[idx];
  }
  const int nb = blockIdx.x * BN;
  // static features (16 per node)
  for (int idx = tid; idx < BN * 16; idx += 256) {
    int n = idx >> 4, f = idx & 15;
    xl[n * K + f] = (nb + n < N) ? xs[(size_t)(nb + n) * 17 + f] : 0.f;
  }
  // LSTM hidden (32 per node)
  for (int idx = tid; idx < BN * 32; idx += 256) {
    int n = idx >> 5, jj = idx & 31;
    float h = 0.f;
    if (nb + n < N) {
      float xr = xs[(size_t)(nb + n) * 17 + 16];
      float gi = xr * W_ih[jj]      + b_ih[jj]      + b_hh[jj];
      float gg = xr * W_ih[64 + jj] + b_ih[64 + jj] + b_hh[64 + jj];
      float go = xr * W_ih[96 + jj] + b_ih[96 + jj] + b_hh[96 + jj];
      float c = sigm(gi) * tanhf(gg);
      h = sigm(go) * tanhf(c);
    }
    xl[n * K + 16 + jj] = h;
  }
  __syncthreads();
  const int colq = tid % COLG;
  const int nodeg = tid / COLG;
  const float4 bv = *(const float4*)&scb[4 * colq];
  float acc[TM][4];
  #pragma unroll
  for (int t = 0; t < TM; ++t) {
    acc[t][0] = bv.x; acc[t][1] = bv.y; acc[t][2] = bv.z; acc[t][3] = bv.w;
  }
  for (int k = 0; k < K; k += 4) {
    const float4 wv0 = *(const float4*)&Wl[(k + 0) * WP + 4 * colq];
    const float4 wv1 = *(const float4*)&Wl[(k + 1) * WP + 4 * colq];
    const float4 wv2 = *(const float4*)&Wl[(k + 2) * WP + 4 * colq];
    const float4 wv3 = *(const float4*)&Wl[(k + 3) * WP + 4 * colq];
    #pragma unroll
    for (int t = 0; t < TM; ++t) {
      const float4 xv = *(const float4*)&xl[(nodeg * TM + t) * K + k];
      acc[t][0] += xv.x * wv0.x + xv.y * wv1.x + xv.z * wv2.x + xv.w * wv3.x;
      acc[t][1] += xv.x * wv0.y + xv.y * wv1.y + xv.z * wv2.y + xv.w * wv3.y;
      acc[t][2] += xv.x * wv0.z + xv.y * wv1.z + xv.z * wv2.z + xv.w * wv3.z;
      acc[t][3] += xv.x * wv0.w + xv.y * wv1.w + xv.z * wv2.w + xv.w * wv3.w;
    }
  }
  #pragma unroll
  for (int t = 0; t < TM; ++t) {
    int n = nb + nodeg * TM + t;
    if (n < N) {
      float4 v = make_float4(fmaxf(acc[t][0], 0.f), fmaxf(acc[t][1], 0.f),
                             fmaxf(acc[t][2], 0.f), fmaxf(acc[t][3], 0.f));
      *(float4*)&out[(size_t)n * M + 4 * colq] = v;
    }
  }
}

// ---------------- per-node attention scores (two roles fused) ----------------
__global__ void a_scores_kernel(const float* __restrict__ xs,
                                const float* __restrict__ attA,
                                const float* __restrict__ attB,
                                float* __restrict__ outA, float* __restrict__ outB, int n) {
  int idx = blockIdx.x * blockDim.x + threadIdx.x;
  if (idx >= n * 8) return;
  int node = idx >> 3, h = idx & 7;
  const float4* xp = (const float4*)(xs + (size_t)node * 128 + h * 16);
  float sa = 0.f, sb = 0.f;
  #pragma unroll
  for (int q4 = 0; q4 < 4; ++q4) {
    float4 x = xp[q4];
    int base = h * 16 + q4 * 4;
    sa += x.x * attA[base + 0]; sb += x.x * attB[base + 0];
    sa += x.y * attA[base + 1]; sb += x.y * attB[base + 1];
    sa += x.z * attA[base + 2]; sb += x.z * attB[base + 2];
    sa += x.w * attA[base + 3]; sb += x.w * attB[base + 3];
  }
  outA[idx] = sa; outB[idx] = sb;
}

// ---------------- fused segment-softmax + aggregation, one wave per dst ----------------
#define AGG_CAP 64
__global__ __launch_bounds__(256) void att_agg_kernel(
    const int* __restrict__ row_ptr, const int* __restrict__ csr_src,
    const float* __restrict__ a_src, const float* __restrict__ a_dst,
    const float* __restrict__ xs_src, float* __restrict__ h_out, int n_dst)
{
  __shared__ float wexp[4][AGG_CAP][8];
  const int lane = threadIdx.x & 63;
  const int w = threadIdx.x >> 6;
  const int dst = blockIdx.x * 4 + w;
  if (dst >= n_dst) return;
  const int start = row_ptr[dst];
  const int deg = row_ptr[dst + 1] - start;
  float ad[8];
  {
    const float4* p = (const float4*)(a_dst + (size_t)dst * 8);
    float4 a0 = p[0], a1 = p[1];
    ad[0]=a0.x; ad[1]=a0.y; ad[2]=a0.z; ad[3]=a0.w;
    ad[4]=a1.x; ad[5]=a1.y; ad[6]=a1.z; ad[7]=a1.w;
  }
  float mh[8];
  #pragma unroll
  for (int h = 0; h < 8; ++h) mh[h] = -3.0e38f;
  for (int jj = lane; jj < deg; jj += 64) {
    int s = csr_src[start + jj];
    const float4* p = (const float4*)(a_src + (size_t)s * 8);
    float4 a0 = p[0], a1 = p[1];
    float lg[8] = {a0.x+ad[0], a0.y+ad[1], a0.z+ad[2], a0.w+ad[3],
                   a1.x+ad[4], a1.y+ad[5], a1.z+ad[6], a1.w+ad[7]};
    #pragma unroll
    for (int h = 0; h < 8; ++h) {
      float v = lg[h];
      v = (v >= 0.f) ? v : 0.2f * v;
      if (jj < AGG_CAP) wexp[w][jj][h] = v;
      mh[h] = fmaxf(mh[h], v);
    }
  }
  #pragma unroll
  for (int off = 32; off; off >>= 1)
    #pragma unroll
    for (int h = 0; h < 8; ++h) mh[h] = fmaxf(mh[h], __shfl_xor(mh[h], off));
  float sh[8] = {0,0,0,0,0,0,0,0};
  for (int jj = lane; jj < deg; jj += 64) {
    float lg[8];
    if (jj < AGG_CAP) {
      #pragma unroll
      for (int h = 0; h < 8; ++h) lg[h] = wexp[w][jj][h];
    } else {
      int s = csr_src[start + jj];
      const float4* p = (const float4*)(a_src + (size_t)s * 8);
      float4 a0 = p[0], a1 = p[1];
      float t[8] = {a0.x+ad[0], a0.y+ad[1], a0.z+ad[2], a0.w+ad[3],
                    a1.x+ad[4], a1.y+ad[5], a1.z+ad[6], a1.w+ad[7]};
      #pragma unroll
      for (int h = 0; h < 8; ++h) { float v = t[h]; lg[h] = (v >= 0.f) ? v : 0.2f * v; }
    }
    #pragma unroll
    for (int h = 0; h < 8; ++h) {
      float e = __expf(lg[h] - mh[h]);
      if (jj < AGG_CAP) wexp[w][jj][h] = e;
      sh[h] += e;
    }
  }
  #pragma unroll
  for (int off = 32; off; off >>= 1)
    #pragma unroll
    for (int h = 0; h < 8; ++h) sh[h] += __shfl_xor(sh[h], off);
  float inv[8];
  #pragma unroll
  for (int h = 0; h < 8; ++h) inv[h] = 1.f / (sh[h] + 1e-16f);
  const int d0 = lane, d1 = lane + 64;
  const int h0 = lane >> 4, h1 = 4 + (lane >> 4);
  float acc0 = 0.f, acc1 = 0.f;
  for (int jj = 0; jj < deg; ++jj) {
    int s = csr_src[start + jj];
    float w0, w1;
    if (jj < AGG_CAP) {
      w0 = wexp[w][jj][h0] * inv[h0];
      w1 = wexp[w][jj][h1] * inv[h1];
    } else {
      float v0 = a_src[(size_t)s * 8 + h0] + ad[h0];
      v0 = (v0 >= 0.f) ? v0 : 0.2f * v0;
      w0 = __expf(v0 - mh[h0]) * inv[h0];
      float v1 = a_src[(size_t)s * 8 + h1] + ad[h1];
      v1 = (v1 >= 0.f) ? v1 : 0.2f * v1;
      w1 = __expf(v1 - mh[h1]) * inv[h1];
    }
    const float* xr = xs_src + (size_t)s * 128;
    acc0 += w0 * xr[d0];
    acc1 += w1 * xr[d1];
  }
  h_out[(size_t)dst * 128 + d0] = fmaxf(acc0, 0.f);
  h_out[(size_t)dst * 128 + d1] = fmaxf(acc1, 0.f);
}

// ---------------- launch ----------------
extern "C" void kernel_launch(void* const* d_in, const int* in_sizes, int n_in,
                              void* d_out, int out_size, void* d_ws, size_t ws_size,
                              hipStream_t stream) {
  (void)in_sizes; (void)n_in; (void)out_size; (void)ws_size;
  const float* x_stream  = (const float*)d_in[0];
  const float* x_device  = (const float*)d_in[1];
  const int*   edge_sd   = (const int*)d_in[2];
  const int*   edge_ds   = (const int*)d_in[3];
  const float* lstm_W_ih = (const float*)d_in[4];
  const float* lstm_b_ih = (const float*)d_in[5];
  const float* lstm_b_hh = (const float*)d_in[6];
  const float* sc_W      = (const float*)d_in[7];
  const float* sc_b      = (const float*)d_in[8];
  const float* dev_W     = (const float*)d_in[9];
  const float* dev_b     = (const float*)d_in[10];
  const float* proj_W    = (const float*)d_in[11];
  const float* proj_b    = (const float*)d_in[12];
  const float* att_src   = (const float*)d_in[13];
  const float* att_dst   = (const float*)d_in[14];
  // d_in[15..17] = q, k_W, k_b — mathematically unused (softmax over singleton stack)
  const float* outp_W1   = (const float*)d_in[18];
  const float* outp_b1   = (const float*)d_in[19];
  const float* outp_W2   = (const float*)d_in[20];
  const float* outp_b2   = (const float*)d_in[21];
  float* out_f = (float*)d_out;

  float* ws = (float*)d_ws;
  size_t off = 0;
  float* h0  = ws + off; off += (size_t)NS_N * 128;
  float* h1  = ws + off; off += (size_t)ND_N * 128;
  float* xs0 = ws + off; off += (size_t)NS_N * 128;
  float* xs1 = ws + off; off += (size_t)ND_N * 128;
  float* as0 = ws + off; off += (size_t)NS_N * 8;
  float* ad0 = ws + off; off += (size_t)NS_N * 8;
  float* as1 = ws + off; off += (size_t)ND_N * 8;
  float* ad1 = ws + off; off += (size_t)ND_N * 8;
  int* ip = (int*)(ws + off);
  int* rp_sd  = ip; ip += ND_N + 1;
  int* rp_ds  = ip; ip += NS_N + 1;
  int* csr_sd = ip; ip += E_N;
  int* csr_ds = ip; ip += E_N;
  int* cnt    = ip; ip += (NS_N > ND_N ? NS_N : ND_N);
  int* fil    = ip;

  const int EB = (E_N + 255) / 256;
  hipMemsetAsync(cnt, 0, ND_N * sizeof(int), stream);
  count_kernel<<<EB, 256, 0, stream>>>(edge_sd + E_N, cnt, E_N);
  exscan_kernel<<<1, 1024, 0, stream>>>(cnt, rp_sd, ND_N);
  hipMemsetAsync(fil, 0, ND_N * sizeof(int), stream);
  fill_kernel<<<EB, 256, 0, stream>>>(edge_sd, edge_sd + E_N, rp_sd, fil, csr_sd, E_N);
  hipMemsetAsync(cnt, 0, NS_N * sizeof(int), stream);
  count_kernel<<<EB, 256, 0, stream>>>(edge_ds + E_N, cnt, E_N);
  exscan_kernel<<<1, 1024, 0, stream>>>(cnt, rp_ds, NS_N);
  hipMemsetAsync(fil, 0, NS_N * sizeof(int), stream);
  fill_kernel<<<EB, 256, 0, stream>>>(edge_ds, edge_ds + E_N, rp_ds, fil, csr_ds, E_N);

  const int GB = (NS_N + 127) / 128;  // 391 blocks (NS_N == ND_N)
  // encoders
  enc_stream2_kernel<<<GB, 256, 0, stream>>>(
      x_stream, lstm_W_ih, lstm_b_ih, lstm_b_hh, sc_W, sc_b, h0, NS_N);
  dense2_kernel<32, 128, 128, true><<<GB, 256, 0, stream>>>(
      x_device, dev_W, dev_b, h1, ND_N);

  // GNN layers
  for (int l = 0; l < 2; ++l) {
    dense2_kernel<128, 128, 128, false><<<GB, 256, 0, stream>>>(
        h0, proj_W + (size_t)(l * 2 + 0) * 16384, proj_b + (l * 2 + 0) * 128, xs0, NS_N);
    dense2_kernel<128, 128, 128, false><<<GB, 256, 0, stream>>>(
        h1, proj_W + (size_t)(l * 2 + 1) * 16384, proj_b + (l * 2 + 1) * 128, xs1, ND_N);
    a_scores_kernel<<<(NS_N * 8 + 255) / 256, 256, 0, stream>>>(
        xs0, att_src + (l * 2 + 0) * 128, att_dst + (l * 2 + 1) * 128, as0, ad0, NS_N);
    a_scores_kernel<<<(ND_N * 8 + 255) / 256, 256, 0, stream>>>(
        xs1, att_src + (l * 2 + 1) * 128, att_dst + (l * 2 + 0) * 128, as1, ad1, ND_N);
    att_agg_kernel<<<(ND_N + 3) / 4, 256, 0, stream>>>(rp_sd, csr_sd, as0, ad1, xs0, h1, ND_N);
    att_agg_kernel<<<(NS_N + 3) / 4, 256, 0, stream>>>(rp_ds, csr_ds, as1, ad0, xs1, h0, NS_N);
  }

  // output heads (xs0/xs1 reused as temps)
  dense2_kernel<128, 64, 128, true><<<GB, 256, 0, stream>>>(
      h0, outp_W1, outp_b1, xs0, NS_N);
  dense2_kernel<64, 64, 128, false><<<GB, 256, 0, stream>>>(
      xs0, outp_W2, outp_b2, out_f, NS_N);
  dense2_kernel<128, 64, 128, true><<<GB, 256, 0, stream>>>(
      h1, outp_W1 + 64 * 128, outp_b1 + 64, xs1, ND_N);
  dense2_kernel<64, 64, 128, false><<<GB, 256, 0, stream>>>(
      xs1, outp_W2 + 64 * 64, outp_b2 + 64, out_f + (size_t)NS_N * 64, ND_N);
}

// Round 4
// 822.103 us; speedup vs baseline: 2.2977x; 1.2481x over previous
//
#include <hip/hip_runtime.h>
#include <hip/hip_bf16.h>
#include <cstdint>

static constexpr int NS_N = 50000;
static constexpr int ND_N = 50000;
static constexpr int E_N  = 500000;

__device__ __forceinline__ float sigm(float x) { return 1.f / (1.f + __expf(-x)); }

// 8-way register select without runtime indexing (avoids scratch)
__device__ __forceinline__ float sel8(const float v[8], int h) {
  float a = (h & 1) ? v[1] : v[0];
  float b = (h & 1) ? v[3] : v[2];
  float c = (h & 1) ? v[5] : v[4];
  float d = (h & 1) ? v[7] : v[6];
  float e = (h & 2) ? b : a;
  float f = (h & 2) ? d : c;
  return (h & 4) ? f : e;
}

// ---------------- CSR build (scan-free) ----------------
__global__ void count2_kernel(const int* __restrict__ dsd, const int* __restrict__ dds,
                              int* __restrict__ cnt, int n) {
  int i = blockIdx.x * blockDim.x + threadIdx.x;
  if (i < n) {
    atomicAdd(&cnt[dsd[i]], 1);
    atomicAdd(&cnt[ND_N + dds[i]], 1);
  }
}

// wave-level bump allocation: rp[i] = exclusive offset within a globally bumped segment
__global__ void alloc_kernel(const int* __restrict__ cnt, int* __restrict__ rp,
                             int* __restrict__ totals, int n) {
  const int y = blockIdx.y;
  const int* c = cnt + (size_t)y * n;
  int* r = rp + (size_t)y * n;
  const int i = blockIdx.x * 256 + threadIdx.x;
  const int lane = threadIdx.x & 63;
  int v = (i < n) ? c[i] : 0;
  int incl = v;
  #pragma unroll
  for (int off = 1; off < 64; off <<= 1) {
    int t = __shfl_up(incl, off);
    if (lane >= off) incl += t;
  }
  int tot = __shfl(incl, 63);
  int base = 0;
  if (lane == 0) base = atomicAdd(&totals[y], tot);
  base = __shfl(base, 0);
  if (i < n) r[i] = base + incl - v;
}

__global__ void fill2_kernel(const int* __restrict__ e_sd, const int* __restrict__ e_ds,
                             const int* __restrict__ rp, int* __restrict__ fil,
                             int* __restrict__ csr_sd, int* __restrict__ csr_ds, int n) {
  const int y = blockIdx.y;
  const int* e = y ? e_ds : e_sd;
  int* csr = y ? csr_ds : csr_sd;
  const int* r = rp + (size_t)y * 50000;
  int* f = fil + (size_t)y * 50000;
  int i = blockIdx.x * blockDim.x + threadIdx.x;
  if (i < n) {
    int d = e[E_N + i];
    int pos = r[d] + atomicAdd(&f[d], 1);
    csr[pos] = e[i];
  }
}

// ---------------- dense3: register-tiled f32 GEMM, x direct from global ----------------
template<int K, int M, int BN, bool RELU, bool SCORES>
__global__ __launch_bounds__(256) void dense3_kernel(
    const float* __restrict__ in_, const float* __restrict__ W,
    const float* __restrict__ b, float* __restrict__ out_,
    const float* __restrict__ attA, const float* __restrict__ attB,
    float* __restrict__ outA, float* __restrict__ outB, int N)
{
  static_assert(M % 4 == 0 && K % 4 == 0, "");
  constexpr int COLG = M / 4;
  constexpr int NODEG = 256 / COLG;
  constexpr int TM = BN / NODEG;
  constexpr int WP = M + 4;
  static_assert(BN % NODEG == 0 && 256 % COLG == 0, "");
  __shared__ float Wl[K * WP];
  const int tid = threadIdx.x;
  for (int idx = tid; idx < M * K; idx += 256) {
    int j = idx / K, k = idx % K;
    Wl[k * WP + j] = W[idx];
  }
  __syncthreads();
  const int colq = tid % COLG;
  const int nodeg = tid / COLG;
  const int nb = blockIdx.x * BN;
  const float* xbase[TM];
  #pragma unroll
  for (int t = 0; t < TM; ++t) {
    int n = nb + nodeg * TM + t;
    xbase[t] = in_ + (size_t)(n < N ? n : N - 1) * K;  // clamp: discard at store
  }
  const float4 bv = *(const float4*)&b[4 * colq];
  float acc[TM][4];
  #pragma unroll
  for (int t = 0; t < TM; ++t) {
    acc[t][0] = bv.x; acc[t][1] = bv.y; acc[t][2] = bv.z; acc[t][3] = bv.w;
  }
  for (int k = 0; k < K; k += 4) {
    const float4 wv0 = *(const float4*)&Wl[(k + 0) * WP + 4 * colq];
    const float4 wv1 = *(const float4*)&Wl[(k + 1) * WP + 4 * colq];
    const float4 wv2 = *(const float4*)&Wl[(k + 2) * WP + 4 * colq];
    const float4 wv3 = *(const float4*)&Wl[(k + 3) * WP + 4 * colq];
    #pragma unroll
    for (int t = 0; t < TM; ++t) {
      const float4 xv = *(const float4*)(xbase[t] + k);
      acc[t][0] += xv.x * wv0.x + xv.y * wv1.x + xv.z * wv2.x + xv.w * wv3.x;
      acc[t][1] += xv.x * wv0.y + xv.y * wv1.y + xv.z * wv2.y + xv.w * wv3.y;
      acc[t][2] += xv.x * wv0.z + xv.y * wv1.z + xv.z * wv2.z + xv.w * wv3.z;
      acc[t][3] += xv.x * wv0.w + xv.y * wv1.w + xv.z * wv2.w + xv.w * wv3.w;
    }
  }
  #pragma unroll
  for (int t = 0; t < TM; ++t) {
    int n = nb + nodeg * TM + t;
    if (n < N) {
      float4 v = make_float4(acc[t][0], acc[t][1], acc[t][2], acc[t][3]);
      if constexpr (RELU) {
        v.x = fmaxf(v.x, 0.f); v.y = fmaxf(v.y, 0.f);
        v.z = fmaxf(v.z, 0.f); v.w = fmaxf(v.w, 0.f);
      }
      *(float4*)&out_[(size_t)n * M + 4 * colq] = v;
    }
  }
  if constexpr (SCORES) {
    const float4 aA = *(const float4*)&attA[4 * colq];
    const float4 aB = *(const float4*)&attB[4 * colq];
    #pragma unroll
    for (int t = 0; t < TM; ++t) {
      float pa = acc[t][0] * aA.x + acc[t][1] * aA.y + acc[t][2] * aA.z + acc[t][3] * aA.w;
      float pb = acc[t][0] * aB.x + acc[t][1] * aB.y + acc[t][2] * aB.z + acc[t][3] * aB.w;
      pa += __shfl_xor(pa, 1); pa += __shfl_xor(pa, 2);
      pb += __shfl_xor(pb, 1); pb += __shfl_xor(pb, 2);
      int n = nb + nodeg * TM + t;
      if ((colq & 3) == 0 && n < N) {
        outA[(size_t)n * 8 + (colq >> 2)] = pa;
        outB[(size_t)n * 8 + (colq >> 2)] = pb;
      }
    }
  }
}

// ---------------- stream encoder: LSTM(1 step) + concat staged, then dense 48->128 ----------------
__global__ __launch_bounds__(256) void enc_stream2_kernel(
    const float* __restrict__ xs,
    const float* __restrict__ W_ih,
    const float* __restrict__ b_ih,
    const float* __restrict__ b_hh,
    const float* __restrict__ scW,
    const float* __restrict__ scb,
    float* __restrict__ out, int N)
{
  constexpr int K = 48, M = 128, BN = 128;
  constexpr int COLG = M / 4, NODEG = 256 / COLG, TM = BN / NODEG, WP = M + 4;
  __shared__ float Wl[K * WP];
  __shared__ float xl[BN * K];
  const int tid = threadIdx.x;
  for (int idx = tid; idx < M * K; idx += 256) {
    int j = idx / K, k = idx % K;
    Wl[k * WP + j] = scW[idx];
  }
  const int nb = blockIdx.x * BN;
  for (int idx = tid; idx < BN * 16; idx += 256) {
    int n = idx >> 4, f = idx & 15;
    xl[n * K + f] = (nb + n < N) ? xs[(size_t)(nb + n) * 17 + f] : 0.f;
  }
  for (int idx = tid; idx < BN * 32; idx += 256) {
    int n = idx >> 5, jj = idx & 31;
    float h = 0.f;
    if (nb + n < N) {
      float xr = xs[(size_t)(nb + n) * 17 + 16];
      float gi = xr * W_ih[jj]      + b_ih[jj]      + b_hh[jj];
      float gg = xr * W_ih[64 + jj] + b_ih[64 + jj] + b_hh[64 + jj];
      float go = xr * W_ih[96 + jj] + b_ih[96 + jj] + b_hh[96 + jj];
      float c = sigm(gi) * tanhf(gg);
      h = sigm(go) * tanhf(c);
    }
    xl[n * K + 16 + jj] = h;
  }
  __syncthreads();
  const int colq = tid % COLG;
  const int nodeg = tid / COLG;
  const float4 bv = *(const float4*)&scb[4 * colq];
  float acc[TM][4];
  #pragma unroll
  for (int t = 0; t < TM; ++t) {
    acc[t][0] = bv.x; acc[t][1] = bv.y; acc[t][2] = bv.z; acc[t][3] = bv.w;
  }
  for (int k = 0; k < K; k += 4) {
    const float4 wv0 = *(const float4*)&Wl[(k + 0) * WP + 4 * colq];
    const float4 wv1 = *(const float4*)&Wl[(k + 1) * WP + 4 * colq];
    const float4 wv2 = *(const float4*)&Wl[(k + 2) * WP + 4 * colq];
    const float4 wv3 = *(const float4*)&Wl[(k + 3) * WP + 4 * colq];
    #pragma unroll
    for (int t = 0; t < TM; ++t) {
      const float4 xv = *(const float4*)&xl[(nodeg * TM + t) * K + k];
      acc[t][0] += xv.x * wv0.x + xv.y * wv1.x + xv.z * wv2.x + xv.w * wv3.x;
      acc[t][1] += xv.x * wv0.y + xv.y * wv1.y + xv.z * wv2.y + xv.w * wv3.y;
      acc[t][2] += xv.x * wv0.z + xv.y * wv1.z + xv.z * wv2.z + xv.w * wv3.z;
      acc[t][3] += xv.x * wv0.w + xv.y * wv1.w + xv.z * wv2.w + xv.w * wv3.w;
    }
  }
  #pragma unroll
  for (int t = 0; t < TM; ++t) {
    int n = nb + nodeg * TM + t;
    if (n < N) {
      float4 v = make_float4(fmaxf(acc[t][0], 0.f), fmaxf(acc[t][1], 0.f),
                             fmaxf(acc[t][2], 0.f), fmaxf(acc[t][3], 0.f));
      *(float4*)&out[(size_t)n * M + 4 * colq] = v;
    }
  }
}

// ---------------- fused segment-softmax + aggregation v2 ----------------
#define CAP 128
__global__ __launch_bounds__(256) void att_agg2_kernel(
    const int* __restrict__ rp, const int* __restrict__ degs, const int* __restrict__ csr,
    const float* __restrict__ a_src, const float* __restrict__ a_dst,
    const float* __restrict__ xs, float* __restrict__ out, int n_dst)
{
  __shared__ float wexp[4][8][CAP + 4];   // [wave][head][edge], pitch 132: conflict-free
  __shared__ int   sidx[4][CAP];
  const int lane = threadIdx.x & 63;
  const int w = threadIdx.x >> 6;
  const int dst = blockIdx.x * 4 + w;
  if (dst >= n_dst) return;
  const int start = rp[dst];
  const int deg = degs[dst];
  const int dcap = deg < CAP ? deg : CAP;
  float ad[8];
  {
    const float4* p = (const float4*)(a_dst + (size_t)dst * 8);
    float4 a0 = p[0], a1 = p[1];
    ad[0]=a0.x; ad[1]=a0.y; ad[2]=a0.z; ad[3]=a0.w;
    ad[4]=a1.x; ad[5]=a1.y; ad[6]=a1.z; ad[7]=a1.w;
  }
  float mh[8];
  #pragma unroll
  for (int h = 0; h < 8; ++h) mh[h] = -3.0e38f;
  for (int jj = lane; jj < dcap; jj += 64) {
    int s = csr[start + jj];
    sidx[w][jj] = s;
    const float4* p = (const float4*)(a_src + (size_t)s * 8);
    float4 a0 = p[0], a1 = p[1];
    float lg[8] = {a0.x+ad[0], a0.y+ad[1], a0.z+ad[2], a0.w+ad[3],
                   a1.x+ad[4], a1.y+ad[5], a1.z+ad[6], a1.w+ad[7]};
    #pragma unroll
    for (int h = 0; h < 8; ++h) {
      float v = lg[h];
      v = (v >= 0.f) ? v : 0.2f * v;
      wexp[w][h][jj] = v;
      mh[h] = fmaxf(mh[h], v);
    }
  }
  for (int jj = CAP + lane; jj < deg; jj += 64) {   // overflow (cold path)
    int s = csr[start + jj];
    const float4* p = (const float4*)(a_src + (size_t)s * 8);
    float4 a0 = p[0], a1 = p[1];
    float lg[8] = {a0.x+ad[0], a0.y+ad[1], a0.z+ad[2], a0.w+ad[3],
                   a1.x+ad[4], a1.y+ad[5], a1.z+ad[6], a1.w+ad[7]};
    #pragma unroll
    for (int h = 0; h < 8; ++h) {
      float v = lg[h];
      v = (v >= 0.f) ? v : 0.2f * v;
      mh[h] = fmaxf(mh[h], v);
    }
  }
  #pragma unroll
  for (int off = 32; off; off >>= 1)
    #pragma unroll
    for (int h = 0; h < 8; ++h) mh[h] = fmaxf(mh[h], __shfl_xor(mh[h], off));
  float sh[8] = {0,0,0,0,0,0,0,0};
  for (int jj = lane; jj < dcap; jj += 64) {
    #pragma unroll
    for (int h = 0; h < 8; ++h) {
      float e = __expf(wexp[w][h][jj] - mh[h]);
      wexp[w][h][jj] = e;
      sh[h] += e;
    }
  }
  for (int jj = CAP + lane; jj < deg; jj += 64) {   // overflow
    int s = csr[start + jj];
    const float4* p = (const float4*)(a_src + (size_t)s * 8);
    float4 a0 = p[0], a1 = p[1];
    float lg[8] = {a0.x+ad[0], a0.y+ad[1], a0.z+ad[2], a0.w+ad[3],
                   a1.x+ad[4], a1.y+ad[5], a1.z+ad[6], a1.w+ad[7]};
    #pragma unroll
    for (int h = 0; h < 8; ++h) {
      float v = lg[h];
      v = (v >= 0.f) ? v : 0.2f * v;
      sh[h] += __expf(v - mh[h]);
    }
  }
  #pragma unroll
  for (int off = 32; off; off >>= 1)
    #pragma unroll
    for (int h = 0; h < 8; ++h) sh[h] += __shfl_xor(sh[h], off);
  const int hh = lane >> 3;
  const float invh = 1.f / (sel8(sh, hh) + 1e-16f);
  const float mhh = sel8(mh, hh);
  const float adh = sel8(ad, hh);
  const int dbase = lane * 2;
  float accx = 0.f, accy = 0.f;
  int jj = 0;
  for (; jj + 2 <= dcap; jj += 2) {
    int s0 = sidx[w][jj], s1 = sidx[w][jj + 1];
    float w0 = wexp[w][hh][jj] * invh;
    float w1 = wexp[w][hh][jj + 1] * invh;
    const float2 x0 = *(const float2*)&xs[(size_t)s0 * 128 + dbase];
    const float2 x1 = *(const float2*)&xs[(size_t)s1 * 128 + dbase];
    accx += w0 * x0.x + w1 * x1.x;
    accy += w0 * x0.y + w1 * x1.y;
  }
  if (jj < dcap) {
    int s0 = sidx[w][jj];
    float w0 = wexp[w][hh][jj] * invh;
    const float2 x0 = *(const float2*)&xs[(size_t)s0 * 128 + dbase];
    accx += w0 * x0.x;
    accy += w0 * x0.y;
  }
  for (jj = CAP; jj < deg; ++jj) {   // overflow
    int s = csr[start + jj];
    float v = a_src[(size_t)s * 8 + hh] + adh;
    v = (v >= 0.f) ? v : 0.2f * v;
    float w0 = __expf(v - mhh) * invh;
    const float2 x0 = *(const float2*)&xs[(size_t)s * 128 + dbase];
    accx += w0 * x0.x;
    accy += w0 * x0.y;
  }
  float2 o = make_float2(fmaxf(accx, 0.f), fmaxf(accy, 0.f));
  *(float2*)&out[(size_t)dst * 128 + dbase] = o;
}

// ---------------- launch ----------------
extern "C" void kernel_launch(void* const* d_in, const int* in_sizes, int n_in,
                              void* d_out, int out_size, void* d_ws, size_t ws_size,
                              hipStream_t stream) {
  (void)in_sizes; (void)n_in; (void)out_size; (void)ws_size;
  const float* x_stream  = (const float*)d_in[0];
  const float* x_device  = (const float*)d_in[1];
  const int*   edge_sd   = (const int*)d_in[2];
  const int*   edge_ds   = (const int*)d_in[3];
  const float* lstm_W_ih = (const float*)d_in[4];
  const float* lstm_b_ih = (const float*)d_in[5];
  const float* lstm_b_hh = (const float*)d_in[6];
  const float* sc_W      = (const float*)d_in[7];
  const float* sc_b      = (const float*)d_in[8];
  const float* dev_W     = (const float*)d_in[9];
  const float* dev_b     = (const float*)d_in[10];
  const float* proj_W    = (const float*)d_in[11];
  const float* proj_b    = (const float*)d_in[12];
  const float* att_src   = (const float*)d_in[13];
  const float* att_dst   = (const float*)d_in[14];
  // d_in[15..17] = q, k_W, k_b — mathematically unused (softmax over singleton stack)
  const float* outp_W1   = (const float*)d_in[18];
  const float* outp_b1   = (const float*)d_in[19];
  const float* outp_W2   = (const float*)d_in[20];
  const float* outp_b2   = (const float*)d_in[21];
  float* out_f = (float*)d_out;

  float* ws = (float*)d_ws;
  size_t off = 0;
  float* h0  = ws + off; off += (size_t)NS_N * 128;
  float* h1  = ws + off; off += (size_t)ND_N * 128;
  float* xs0 = ws + off; off += (size_t)NS_N * 128;
  float* xs1 = ws + off; off += (size_t)ND_N * 128;
  float* as0 = ws + off; off += (size_t)NS_N * 8;
  float* ad0 = ws + off; off += (size_t)NS_N * 8;
  float* as1 = ws + off; off += (size_t)ND_N * 8;
  float* ad1 = ws + off; off += (size_t)ND_N * 8;
  int* ip = (int*)(ws + off);
  int* cnt    = ip; ip += ND_N + NS_N;       // [cnt_sd | cnt_ds]
  int* fil    = ip; ip += ND_N + NS_N;       // [fil_sd | fil_ds]
  int* totals = ip; ip += 2;
  int* rp     = ip; ip += ND_N + NS_N;       // [rp_sd | rp_ds]
  int* csr_sd = ip; ip += E_N;
  int* csr_ds = ip; ip += E_N;

  hipMemsetAsync(cnt, 0, (size_t)(2 * (ND_N + NS_N) + 2) * sizeof(int), stream);

  const int EB = (E_N + 255) / 256;
  count2_kernel<<<EB, 256, 0, stream>>>(edge_sd + E_N, edge_ds + E_N, cnt, E_N);
  alloc_kernel<<<dim3((50000 + 255) / 256, 2), 256, 0, stream>>>(cnt, rp, totals, 50000);
  fill2_kernel<<<dim3(EB, 2), 256, 0, stream>>>(edge_sd, edge_ds, rp, fil, csr_sd, csr_ds, E_N);

  const int GB = (NS_N + 127) / 128;  // NS_N == ND_N
  enc_stream2_kernel<<<GB, 256, 0, stream>>>(
      x_stream, lstm_W_ih, lstm_b_ih, lstm_b_hh, sc_W, sc_b, h0, NS_N);
  dense3_kernel<32, 128, 128, true, false><<<GB, 256, 0, stream>>>(
      x_device, dev_W, dev_b, h1, nullptr, nullptr, nullptr, nullptr, ND_N);

  for (int l = 0; l < 2; ++l) {
    dense3_kernel<128, 128, 128, false, true><<<GB, 256, 0, stream>>>(
        h0, proj_W + (size_t)(l * 2 + 0) * 16384, proj_b + (l * 2 + 0) * 128, xs0,
        att_src + (l * 2 + 0) * 128, att_dst + (l * 2 + 1) * 128, as0, ad0, NS_N);
    dense3_kernel<128, 128, 128, false, true><<<GB, 256, 0, stream>>>(
        h1, proj_W + (size_t)(l * 2 + 1) * 16384, proj_b + (l * 2 + 1) * 128, xs1,
        att_src + (l * 2 + 1) * 128, att_dst + (l * 2 + 0) * 128, as1, ad1, ND_N);
    att_agg2_kernel<<<(ND_N + 3) / 4, 256, 0, stream>>>(
        rp, cnt, csr_sd, as0, ad1, xs0, h1, ND_N);
    att_agg2_kernel<<<(NS_N + 3) / 4, 256, 0, stream>>>(
        rp + 50000, cnt + 50000, csr_ds, as1, ad0, xs1, h0, NS_N);
  }

  dense3_kernel<128, 64, 128, true, false><<<GB, 256, 0, stream>>>(
      h0, outp_W1, outp_b1, xs0, nullptr, nullptr, nullptr, nullptr, NS_N);
  dense3_kernel<64, 64, 128, false, false><<<GB, 256, 0, stream>>>(
      xs0, outp_W2, outp_b2, out_f, nullptr, nullptr, nullptr, nullptr, NS_N);
  dense3_kernel<128, 64, 128, true, false><<<GB, 256, 0, stream>>>(
      h1, outp_W1 + 64 * 128, outp_b1 + 64, xs1, nullptr, nullptr, nullptr, nullptr, ND_N);
  dense3_kernel<64, 64, 128, false, false><<<GB, 256, 0, stream>>>(
      xs1, outp_W2 + 64 * 64, outp_b2 + 64, out_f + (size_t)NS_N * 64,
      nullptr, nullptr, nullptr, nullptr, ND_N);
}

// Round 5
// 786.201 us; speedup vs baseline: 2.4026x; 1.0457x over previous
//
#include <hip/hip_runtime.h>
#include <hip/hip_bf16.h>
#include <cstdint>

static constexpr int NS_N = 50000;
static constexpr int ND_N = 50000;
static constexpr int E_N  = 500000;

__device__ __forceinline__ float sigm(float x) { return 1.f / (1.f + __expf(-x)); }

// 8-way register select without runtime indexing (avoids scratch)
__device__ __forceinline__ float sel8(const float v[8], int h) {
  float a = (h & 1) ? v[1] : v[0];
  float b = (h & 1) ? v[3] : v[2];
  float c = (h & 1) ? v[5] : v[4];
  float d = (h & 1) ? v[7] : v[6];
  float e = (h & 2) ? b : a;
  float f = (h & 2) ? d : c;
  return (h & 4) ? f : e;
}

// ---------------- CSR build (scan-free) ----------------
__global__ void count2_kernel(const int* __restrict__ dsd, const int* __restrict__ dds,
                              int* __restrict__ cnt, int n) {
  int i = blockIdx.x * blockDim.x + threadIdx.x;
  if (i < n) {
    atomicAdd(&cnt[dsd[i]], 1);
    atomicAdd(&cnt[ND_N + dds[i]], 1);
  }
}

// wave-level bump allocation: rp[i] = exclusive offset within a globally bumped segment
__global__ void alloc_kernel(const int* __restrict__ cnt, int* __restrict__ rp,
                             int* __restrict__ totals, int n) {
  const int y = blockIdx.y;
  const int* c = cnt + (size_t)y * n;
  int* r = rp + (size_t)y * n;
  const int i = blockIdx.x * 256 + threadIdx.x;
  const int lane = threadIdx.x & 63;
  int v = (i < n) ? c[i] : 0;
  int incl = v;
  #pragma unroll
  for (int off = 1; off < 64; off <<= 1) {
    int t = __shfl_up(incl, off);
    if (lane >= off) incl += t;
  }
  int tot = __shfl(incl, 63);
  int base = 0;
  if (lane == 0) base = atomicAdd(&totals[y], tot);
  base = __shfl(base, 0);
  if (i < n) r[i] = base + incl - v;
}

__global__ void fill2_kernel(const int* __restrict__ e_sd, const int* __restrict__ e_ds,
                             const int* __restrict__ rp, int* __restrict__ fil,
                             int* __restrict__ csr_sd, int* __restrict__ csr_ds, int n) {
  const int y = blockIdx.y;
  const int* e = y ? e_ds : e_sd;
  int* csr = y ? csr_ds : csr_sd;
  const int* r = rp + (size_t)y * 50000;
  int* f = fil + (size_t)y * 50000;
  int i = blockIdx.x * blockDim.x + threadIdx.x;
  if (i < n) {
    int d = e[E_N + i];
    int pos = r[d] + atomicAdd(&f[d], 1);
    csr[pos] = e[i];
  }
}

// ---------------- dense5: register-tiled f32 GEMM, K-split LDS staging, dual dispatch ----------------
// LDS = 64*(M+4)*4 bytes max (33.8 KB for M=128) -> 4 blocks/CU. gridDim.y=2 when DUAL.
template<int K, int M, int BN, bool RELU, bool SCORES, bool DUAL>
__global__ __launch_bounds__(256) void dense5_kernel(
    const float* __restrict__ in0, const float* __restrict__ W0,
    const float* __restrict__ b0, float* __restrict__ out0,
    const float* __restrict__ aA0, const float* __restrict__ aB0,
    float* __restrict__ oA0, float* __restrict__ oB0,
    const float* __restrict__ in1, const float* __restrict__ W1,
    const float* __restrict__ b1, float* __restrict__ out1,
    const float* __restrict__ aA1, const float* __restrict__ aB1,
    float* __restrict__ oA1, float* __restrict__ oB1, int N)
{
  static_assert(M % 4 == 0 && K % 4 == 0, "");
  constexpr int KH = (K > 64) ? 64 : K;
  constexpr int COLG = M / 4;
  constexpr int NODEG = 256 / COLG;
  constexpr int TM = BN / NODEG;
  constexpr int WP = M + 4;
  static_assert(BN % NODEG == 0 && 256 % COLG == 0 && K % KH == 0, "");
  const float* in_ = in0; const float* W = W0; const float* b = b0; float* out_ = out0;
  const float* aA = aA0; const float* aB = aB0; float* oA = oA0; float* oB = oB0;
  if constexpr (DUAL) {
    if (blockIdx.y) {
      in_ = in1; W = W1; b = b1; out_ = out1;
      aA = aA1; aB = aB1; oA = oA1; oB = oB1;
    }
  }
  __shared__ float Wl[KH * WP];
  const int tid = threadIdx.x;
  const int colq = tid % COLG;
  const int nodeg = tid / COLG;
  const int nb = blockIdx.x * BN;
  const float* xbase[TM];
  #pragma unroll
  for (int t = 0; t < TM; ++t) {
    int n = nb + nodeg * TM + t;
    xbase[t] = in_ + (size_t)(n < N ? n : N - 1) * K;  // clamp: discard at store
  }
  const float4 bv = *(const float4*)&b[4 * colq];
  float acc[TM][4];
  #pragma unroll
  for (int t = 0; t < TM; ++t) {
    acc[t][0] = bv.x; acc[t][1] = bv.y; acc[t][2] = bv.z; acc[t][3] = bv.w;
  }
  for (int ks = 0; ks < K; ks += KH) {
    if (ks) __syncthreads();
    for (int idx = tid; idx < M * KH; idx += 256) {
      int j = idx / KH, kk = idx % KH;
      Wl[kk * WP + j] = W[(size_t)j * K + ks + kk];
    }
    __syncthreads();
    for (int k2 = 0; k2 < KH; k2 += 4) {
      const float4 wv0 = *(const float4*)&Wl[(k2 + 0) * WP + 4 * colq];
      const float4 wv1 = *(const float4*)&Wl[(k2 + 1) * WP + 4 * colq];
      const float4 wv2 = *(const float4*)&Wl[(k2 + 2) * WP + 4 * colq];
      const float4 wv3 = *(const float4*)&Wl[(k2 + 3) * WP + 4 * colq];
      #pragma unroll
      for (int t = 0; t < TM; ++t) {
        const float4 xv = *(const float4*)(xbase[t] + ks + k2);
        acc[t][0] += xv.x * wv0.x + xv.y * wv1.x + xv.z * wv2.x + xv.w * wv3.x;
        acc[t][1] += xv.x * wv0.y + xv.y * wv1.y + xv.z * wv2.y + xv.w * wv3.y;
        acc[t][2] += xv.x * wv0.z + xv.y * wv1.z + xv.z * wv2.z + xv.w * wv3.z;
        acc[t][3] += xv.x * wv0.w + xv.y * wv1.w + xv.z * wv2.w + xv.w * wv3.w;
      }
    }
  }
  #pragma unroll
  for (int t = 0; t < TM; ++t) {
    int n = nb + nodeg * TM + t;
    if (n < N) {
      float4 v = make_float4(acc[t][0], acc[t][1], acc[t][2], acc[t][3]);
      if constexpr (RELU) {
        v.x = fmaxf(v.x, 0.f); v.y = fmaxf(v.y, 0.f);
        v.z = fmaxf(v.z, 0.f); v.w = fmaxf(v.w, 0.f);
      }
      *(float4*)&out_[(size_t)n * M + 4 * colq] = v;
    }
  }
  if constexpr (SCORES) {
    const float4 vA = *(const float4*)&aA[4 * colq];
    const float4 vB = *(const float4*)&aB[4 * colq];
    #pragma unroll
    for (int t = 0; t < TM; ++t) {
      float pa = acc[t][0] * vA.x + acc[t][1] * vA.y + acc[t][2] * vA.z + acc[t][3] * vA.w;
      float pb = acc[t][0] * vB.x + acc[t][1] * vB.y + acc[t][2] * vB.z + acc[t][3] * vB.w;
      pa += __shfl_xor(pa, 1); pa += __shfl_xor(pa, 2);
      pb += __shfl_xor(pb, 1); pb += __shfl_xor(pb, 2);
      int n = nb + nodeg * TM + t;
      if ((colq & 3) == 0 && n < N) {
        oA[(size_t)n * 8 + (colq >> 2)] = pa;
        oB[(size_t)n * 8 + (colq >> 2)] = pb;
      }
    }
  }
}

// ---------------- stream encoder: LSTM(1 step) + concat staged, then dense 48->128 ----------------
__global__ __launch_bounds__(256) void enc_stream2_kernel(
    const float* __restrict__ xs,
    const float* __restrict__ W_ih,
    const float* __restrict__ b_ih,
    const float* __restrict__ b_hh,
    const float* __restrict__ scW,
    const float* __restrict__ scb,
    float* __restrict__ out, int N)
{
  constexpr int K = 48, M = 128, BN = 128;
  constexpr int COLG = M / 4, NODEG = 256 / COLG, TM = BN / NODEG, WP = M + 4;
  __shared__ float Wl[K * WP];
  __shared__ float xl[BN * K];
  const int tid = threadIdx.x;
  for (int idx = tid; idx < M * K; idx += 256) {
    int j = idx / K, k = idx % K;
    Wl[k * WP + j] = scW[idx];
  }
  const int nb = blockIdx.x * BN;
  for (int idx = tid; idx < BN * 16; idx += 256) {
    int n = idx >> 4, f = idx & 15;
    xl[n * K + f] = (nb + n < N) ? xs[(size_t)(nb + n) * 17 + f] : 0.f;
  }
  for (int idx = tid; idx < BN * 32; idx += 256) {
    int n = idx >> 5, jj = idx & 31;
    float h = 0.f;
    if (nb + n < N) {
      float xr = xs[(size_t)(nb + n) * 17 + 16];
      float gi = xr * W_ih[jj]      + b_ih[jj]      + b_hh[jj];
      float gg = xr * W_ih[64 + jj] + b_ih[64 + jj] + b_hh[64 + jj];
      float go = xr * W_ih[96 + jj] + b_ih[96 + jj] + b_hh[96 + jj];
      float c = sigm(gi) * tanhf(gg);
      h = sigm(go) * tanhf(c);
    }
    xl[n * K + 16 + jj] = h;
  }
  __syncthreads();
  const int colq = tid % COLG;
  const int nodeg = tid / COLG;
  const float4 bv = *(const float4*)&scb[4 * colq];
  float acc[TM][4];
  #pragma unroll
  for (int t = 0; t < TM; ++t) {
    acc[t][0] = bv.x; acc[t][1] = bv.y; acc[t][2] = bv.z; acc[t][3] = bv.w;
  }
  for (int k = 0; k < K; k += 4) {
    const float4 wv0 = *(const float4*)&Wl[(k + 0) * WP + 4 * colq];
    const float4 wv1 = *(const float4*)&Wl[(k + 1) * WP + 4 * colq];
    const float4 wv2 = *(const float4*)&Wl[(k + 2) * WP + 4 * colq];
    const float4 wv3 = *(const float4*)&Wl[(k + 3) * WP + 4 * colq];
    #pragma unroll
    for (int t = 0; t < TM; ++t) {
      const float4 xv = *(const float4*)&xl[(nodeg * TM + t) * K + k];
      acc[t][0] += xv.x * wv0.x + xv.y * wv1.x + xv.z * wv2.x + xv.w * wv3.x;
      acc[t][1] += xv.x * wv0.y + xv.y * wv1.y + xv.z * wv2.y + xv.w * wv3.y;
      acc[t][2] += xv.x * wv0.z + xv.y * wv1.z + xv.z * wv2.z + xv.w * wv3.z;
      acc[t][3] += xv.x * wv0.w + xv.y * wv1.w + xv.z * wv2.w + xv.w * wv3.w;
    }
  }
  #pragma unroll
  for (int t = 0; t < TM; ++t) {
    int n = nb + nodeg * TM + t;
    if (n < N) {
      float4 v = make_float4(fmaxf(acc[t][0], 0.f), fmaxf(acc[t][1], 0.f),
                             fmaxf(acc[t][2], 0.f), fmaxf(acc[t][3], 0.f));
      *(float4*)&out[(size_t)n * M + 4 * colq] = v;
    }
  }
}

// ---------------- fused segment-softmax + aggregation v3: both edge types in one dispatch ----------------
#define CAP 128
__global__ __launch_bounds__(256) void att_agg3_kernel(
    const int* __restrict__ rp0, const int* __restrict__ dg0, const int* __restrict__ csr0,
    const float* __restrict__ asrc0, const float* __restrict__ adst0,
    const float* __restrict__ x0, float* __restrict__ o0,
    const int* __restrict__ rp1, const int* __restrict__ dg1, const int* __restrict__ csr1,
    const float* __restrict__ asrc1, const float* __restrict__ adst1,
    const float* __restrict__ x1, float* __restrict__ o1, int n_dst)
{
  const int y = blockIdx.y;
  const int* rp    = y ? rp1 : rp0;
  const int* dgs   = y ? dg1 : dg0;
  const int* csr   = y ? csr1 : csr0;
  const float* a_src = y ? asrc1 : asrc0;
  const float* a_dst = y ? adst1 : adst0;
  const float* xs  = y ? x1 : x0;
  float* out       = y ? o1 : o0;

  __shared__ float wexp[4][8][CAP + 4];   // [wave][head][edge], pitch 132: conflict-free
  __shared__ int   sidx[4][CAP];
  const int lane = threadIdx.x & 63;
  const int w = threadIdx.x >> 6;
  const int dst = blockIdx.x * 4 + w;
  if (dst >= n_dst) return;
  const int start = rp[dst];
  const int deg = dgs[dst];
  const int dcap = deg < CAP ? deg : CAP;
  float ad[8];
  {
    const float4* p = (const float4*)(a_dst + (size_t)dst * 8);
    float4 a0 = p[0], a1 = p[1];
    ad[0]=a0.x; ad[1]=a0.y; ad[2]=a0.z; ad[3]=a0.w;
    ad[4]=a1.x; ad[5]=a1.y; ad[6]=a1.z; ad[7]=a1.w;
  }
  float mh[8];
  #pragma unroll
  for (int h = 0; h < 8; ++h) mh[h] = -3.0e38f;
  for (int jj = lane; jj < dcap; jj += 64) {
    int s = csr[start + jj];
    sidx[w][jj] = s;
    const float4* p = (const float4*)(a_src + (size_t)s * 8);
    float4 a0 = p[0], a1 = p[1];
    float lg[8] = {a0.x+ad[0], a0.y+ad[1], a0.z+ad[2], a0.w+ad[3],
                   a1.x+ad[4], a1.y+ad[5], a1.z+ad[6], a1.w+ad[7]};
    #pragma unroll
    for (int h = 0; h < 8; ++h) {
      float v = lg[h];
      v = (v >= 0.f) ? v : 0.2f * v;
      wexp[w][h][jj] = v;
      mh[h] = fmaxf(mh[h], v);
    }
  }
  for (int jj = CAP + lane; jj < deg; jj += 64) {   // overflow (cold path)
    int s = csr[start + jj];
    const float4* p = (const float4*)(a_src + (size_t)s * 8);
    float4 a0 = p[0], a1 = p[1];
    float lg[8] = {a0.x+ad[0], a0.y+ad[1], a0.z+ad[2], a0.w+ad[3],
                   a1.x+ad[4], a1.y+ad[5], a1.z+ad[6], a1.w+ad[7]};
    #pragma unroll
    for (int h = 0; h < 8; ++h) {
      float v = lg[h];
      v = (v >= 0.f) ? v : 0.2f * v;
      mh[h] = fmaxf(mh[h], v);
    }
  }
  #pragma unroll
  for (int off = 32; off; off >>= 1)
    #pragma unroll
    for (int h = 0; h < 8; ++h) mh[h] = fmaxf(mh[h], __shfl_xor(mh[h], off));
  float sh[8] = {0,0,0,0,0,0,0,0};
  for (int jj = lane; jj < dcap; jj += 64) {
    #pragma unroll
    for (int h = 0; h < 8; ++h) {
      float e = __expf(wexp[w][h][jj] - mh[h]);
      wexp[w][h][jj] = e;
      sh[h] += e;
    }
  }
  for (int jj = CAP + lane; jj < deg; jj += 64) {   // overflow
    int s = csr[start + jj];
    const float4* p = (const float4*)(a_src + (size_t)s * 8);
    float4 a0 = p[0], a1 = p[1];
    float lg[8] = {a0.x+ad[0], a0.y+ad[1], a0.z+ad[2], a0.w+ad[3],
                   a1.x+ad[4], a1.y+ad[5], a1.z+ad[6], a1.w+ad[7]};
    #pragma unroll
    for (int h = 0; h < 8; ++h) {
      float v = lg[h];
      v = (v >= 0.f) ? v : 0.2f * v;
      sh[h] += __expf(v - mh[h]);
    }
  }
  #pragma unroll
  for (int off = 32; off; off >>= 1)
    #pragma unroll
    for (int h = 0; h < 8; ++h) sh[h] += __shfl_xor(sh[h], off);
  const int hh = lane >> 3;
  const float invh = 1.f / (sel8(sh, hh) + 1e-16f);
  const float mhh = sel8(mh, hh);
  const float adh = sel8(ad, hh);
  // pass 3: unnormalized weighted sum (invh applied once at the end), unroll x4
  const int dbase = lane * 2;
  float ax0 = 0.f, ay0 = 0.f, ax1 = 0.f, ay1 = 0.f;
  int jj = 0;
  for (; jj + 4 <= dcap; jj += 4) {
    int s0 = sidx[w][jj], s1 = sidx[w][jj+1], s2 = sidx[w][jj+2], s3 = sidx[w][jj+3];
    float w0 = wexp[w][hh][jj], w1 = wexp[w][hh][jj+1];
    float w2 = wexp[w][hh][jj+2], w3 = wexp[w][hh][jj+3];
    const float2 v0 = *(const float2*)&xs[(size_t)s0 * 128 + dbase];
    const float2 v1 = *(const float2*)&xs[(size_t)s1 * 128 + dbase];
    const float2 v2 = *(const float2*)&xs[(size_t)s2 * 128 + dbase];
    const float2 v3 = *(const float2*)&xs[(size_t)s3 * 128 + dbase];
    ax0 += w0 * v0.x + w1 * v1.x;  ay0 += w0 * v0.y + w1 * v1.y;
    ax1 += w2 * v2.x + w3 * v3.x;  ay1 += w2 * v2.y + w3 * v3.y;
  }
  for (; jj < dcap; ++jj) {
    int s0 = sidx[w][jj];
    float w0 = wexp[w][hh][jj];
    const float2 v0 = *(const float2*)&xs[(size_t)s0 * 128 + dbase];
    ax0 += w0 * v0.x;
    ay0 += w0 * v0.y;
  }
  for (jj = CAP; jj < deg; ++jj) {   // overflow
    int s = csr[start + jj];
    float v = a_src[(size_t)s * 8 + hh] + adh;
    v = (v >= 0.f) ? v : 0.2f * v;
    float w0 = __expf(v - mhh);
    const float2 v0 = *(const float2*)&xs[(size_t)s * 128 + dbase];
    ax0 += w0 * v0.x;
    ay0 += w0 * v0.y;
  }
  float2 o = make_float2(fmaxf((ax0 + ax1) * invh, 0.f), fmaxf((ay0 + ay1) * invh, 0.f));
  *(float2*)&out[(size_t)dst * 128 + dbase] = o;
}

// ---------------- launch ----------------
extern "C" void kernel_launch(void* const* d_in, const int* in_sizes, int n_in,
                              void* d_out, int out_size, void* d_ws, size_t ws_size,
                              hipStream_t stream) {
  (void)in_sizes; (void)n_in; (void)out_size; (void)ws_size;
  const float* x_stream  = (const float*)d_in[0];
  const float* x_device  = (const float*)d_in[1];
  const int*   edge_sd   = (const int*)d_in[2];
  const int*   edge_ds   = (const int*)d_in[3];
  const float* lstm_W_ih = (const float*)d_in[4];
  const float* lstm_b_ih = (const float*)d_in[5];
  const float* lstm_b_hh = (const float*)d_in[6];
  const float* sc_W      = (const float*)d_in[7];
  const float* sc_b      = (const float*)d_in[8];
  const float* dev_W     = (const float*)d_in[9];
  const float* dev_b     = (const float*)d_in[10];
  const float* proj_W    = (const float*)d_in[11];
  const float* proj_b    = (const float*)d_in[12];
  const float* att_src   = (const float*)d_in[13];
  const float* att_dst   = (const float*)d_in[14];
  // d_in[15..17] = q, k_W, k_b — mathematically unused (softmax over singleton stack)
  const float* outp_W1   = (const float*)d_in[18];
  const float* outp_b1   = (const float*)d_in[19];
  const float* outp_W2   = (const float*)d_in[20];
  const float* outp_b2   = (const float*)d_in[21];
  float* out_f = (float*)d_out;

  float* ws = (float*)d_ws;
  size_t off = 0;
  float* h0  = ws + off; off += (size_t)NS_N * 128;
  float* h1  = ws + off; off += (size_t)ND_N * 128;
  float* xs0 = ws + off; off += (size_t)NS_N * 128;
  float* xs1 = ws + off; off += (size_t)ND_N * 128;
  float* as0 = ws + off; off += (size_t)NS_N * 8;
  float* ad0 = ws + off; off += (size_t)NS_N * 8;
  float* as1 = ws + off; off += (size_t)ND_N * 8;
  float* ad1 = ws + off; off += (size_t)ND_N * 8;
  int* ip = (int*)(ws + off);
  int* cnt    = ip; ip += ND_N + NS_N;       // [cnt_sd | cnt_ds]
  int* fil    = ip; ip += ND_N + NS_N;       // [fil_sd | fil_ds]
  int* totals = ip; ip += 2;
  int* rp     = ip; ip += ND_N + NS_N;       // [rp_sd | rp_ds]
  int* csr_sd = ip; ip += E_N;
  int* csr_ds = ip; ip += E_N;

  hipMemsetAsync(cnt, 0, (size_t)(2 * (ND_N + NS_N) + 2) * sizeof(int), stream);

  const int EB = (E_N + 255) / 256;
  count2_kernel<<<EB, 256, 0, stream>>>(edge_sd + E_N, edge_ds + E_N, cnt, E_N);
  alloc_kernel<<<dim3((50000 + 255) / 256, 2), 256, 0, stream>>>(cnt, rp, totals, 50000);
  fill2_kernel<<<dim3(EB, 2), 256, 0, stream>>>(edge_sd, edge_ds, rp, fil, csr_sd, csr_ds, E_N);

  const int GB64 = (NS_N + 63) / 64;    // 782 blocks (BN=64)
  const int GB128 = (NS_N + 127) / 128; // 391 blocks (enc_stream)

  enc_stream2_kernel<<<GB128, 256, 0, stream>>>(
      x_stream, lstm_W_ih, lstm_b_ih, lstm_b_hh, sc_W, sc_b, h0, NS_N);
  dense5_kernel<32, 128, 64, true, false, false><<<GB64, 256, 0, stream>>>(
      x_device, dev_W, dev_b, h1, nullptr, nullptr, nullptr, nullptr,
      nullptr, nullptr, nullptr, nullptr, nullptr, nullptr, nullptr, nullptr, ND_N);

  for (int l = 0; l < 2; ++l) {
    // dual projection + fused attention scores
    dense5_kernel<128, 128, 64, false, true, true><<<dim3(GB64, 2), 256, 0, stream>>>(
        h0, proj_W + (size_t)(l * 2 + 0) * 16384, proj_b + (l * 2 + 0) * 128, xs0,
        att_src + (l * 2 + 0) * 128, att_dst + (l * 2 + 1) * 128, as0, ad0,
        h1, proj_W + (size_t)(l * 2 + 1) * 16384, proj_b + (l * 2 + 1) * 128, xs1,
        att_src + (l * 2 + 1) * 128, att_dst + (l * 2 + 0) * 128, as1, ad1, NS_N);
    // fused aggregation for both edge types
    att_agg3_kernel<<<dim3((ND_N + 3) / 4, 2), 256, 0, stream>>>(
        rp, cnt, csr_sd, as0, ad1, xs0, h1,
        rp + 50000, cnt + 50000, csr_ds, as1, ad0, xs1, h0, ND_N);
  }

  // output heads, dual (xs0/xs1 reused as temps)
  dense5_kernel<128, 64, 64, true, false, true><<<dim3(GB64, 2), 256, 0, stream>>>(
      h0, outp_W1, outp_b1, xs0, nullptr, nullptr, nullptr, nullptr,
      h1, outp_W1 + 64 * 128, outp_b1 + 64, xs1, nullptr, nullptr, nullptr, nullptr, NS_N);
  dense5_kernel<64, 64, 64, false, false, true><<<dim3(GB64, 2), 256, 0, stream>>>(
      xs0, outp_W2, outp_b2, out_f, nullptr, nullptr, nullptr, nullptr,
      xs1, outp_W2 + 64 * 64, outp_b2 + 64, out_f + (size_t)NS_N * 64,
      nullptr, nullptr, nullptr, nullptr, NS_N);
}

// Round 6
// 648.496 us; speedup vs baseline: 2.9128x; 1.2123x over previous
//
#include <hip/hip_runtime.h>
#include <hip/hip_bf16.h>
#include <cstdint>

static constexpr int NS_N = 50000;
static constexpr int ND_N = 50000;
static constexpr int E_N  = 500000;

__device__ __forceinline__ float sigm(float x) { return 1.f / (1.f + __expf(-x)); }

__device__ __forceinline__ unsigned short f2bf(float f) {
  __hip_bfloat16 h = __float2bfloat16(f);   // RTNE
  return *reinterpret_cast<unsigned short*>(&h);
}

// 8-way register select without runtime indexing (avoids scratch)
__device__ __forceinline__ float sel8(const float v[8], int h) {
  float a = (h & 1) ? v[1] : v[0];
  float b = (h & 1) ? v[3] : v[2];
  float c = (h & 1) ? v[5] : v[4];
  float d = (h & 1) ? v[7] : v[6];
  float e = (h & 2) ? b : a;
  float f = (h & 2) ? d : c;
  return (h & 4) ? f : e;
}

// ---------------- CSR build (scan-free) ----------------
__global__ void count2_kernel(const int* __restrict__ dsd, const int* __restrict__ dds,
                              int* __restrict__ cnt, int n) {
  int i = blockIdx.x * blockDim.x + threadIdx.x;
  if (i < n) {
    atomicAdd(&cnt[dsd[i]], 1);
    atomicAdd(&cnt[ND_N + dds[i]], 1);
  }
}

// wave-level bump allocation: rp[i] = start offset; cur[i] = running cursor for fill
__global__ void alloc_kernel(const int* __restrict__ cnt, int* __restrict__ rp,
                             int* __restrict__ cur, int* __restrict__ totals, int n) {
  const int y = blockIdx.y;
  const int* c = cnt + (size_t)y * n;
  int* r = rp + (size_t)y * n;
  int* q = cur + (size_t)y * n;
  const int i = blockIdx.x * 256 + threadIdx.x;
  const int lane = threadIdx.x & 63;
  int v = (i < n) ? c[i] : 0;
  int incl = v;
  #pragma unroll
  for (int off = 1; off < 64; off <<= 1) {
    int t = __shfl_up(incl, off);
    if (lane >= off) incl += t;
  }
  int tot = __shfl(incl, 63);
  int base = 0;
  if (lane == 0) base = atomicAdd(&totals[y], tot);
  base = __shfl(base, 0);
  if (i < n) {
    int st = base + incl - v;
    r[i] = st;
    q[i] = st;
  }
}

__global__ void fill2_kernel(const int* __restrict__ e_sd, const int* __restrict__ e_ds,
                             int* __restrict__ cur,
                             int* __restrict__ csr_sd, int* __restrict__ csr_ds, int n) {
  const int y = blockIdx.y;
  const int* e = y ? e_ds : e_sd;
  int* csr = y ? csr_ds : csr_sd;
  int* q = cur + (size_t)y * 50000;
  int i = blockIdx.x * blockDim.x + threadIdx.x;
  if (i < n) {
    int d = e[E_N + i];
    int pos = atomicAdd(&q[d], 1);
    csr[pos] = e[i];
  }
}

// ---------------- dense6: register-tiled f32 GEMM, K-split LDS staging, dual dispatch ----------------
// SCORES mode: writes bf16 output + per-head attention scores (no f32 output).
template<int K, int M, int BN, bool RELU, bool SCORES, bool DUAL>
__global__ __launch_bounds__(256) void dense6_kernel(
    const float* __restrict__ in0, const float* __restrict__ W0,
    const float* __restrict__ b0, void* __restrict__ out0,
    const float* __restrict__ aA0, const float* __restrict__ aB0,
    float* __restrict__ oA0, float* __restrict__ oB0,
    const float* __restrict__ in1, const float* __restrict__ W1x,
    const float* __restrict__ b1x, void* __restrict__ out1,
    const float* __restrict__ aA1, const float* __restrict__ aB1,
    float* __restrict__ oA1, float* __restrict__ oB1, int N)
{
  static_assert(M % 4 == 0 && K % 4 == 0, "");
  constexpr int KH = (K > 64) ? 64 : K;
  constexpr int COLG = M / 4;
  constexpr int NODEG = 256 / COLG;
  constexpr int TM = BN / NODEG;
  constexpr int WP = M + 4;
  static_assert(BN % NODEG == 0 && 256 % COLG == 0 && K % KH == 0, "");
  const float* in_ = in0; const float* W = W0; const float* b = b0; void* out_ = out0;
  const float* aA = aA0; const float* aB = aB0; float* oA = oA0; float* oB = oB0;
  if constexpr (DUAL) {
    if (blockIdx.y) {
      in_ = in1; W = W1x; b = b1x; out_ = out1;
      aA = aA1; aB = aB1; oA = oA1; oB = oB1;
    }
  }
  __shared__ float Wl[KH * WP];
  const int tid = threadIdx.x;
  const int colq = tid % COLG;
  const int nodeg = tid / COLG;
  const int nb = blockIdx.x * BN;
  const float* xbase[TM];
  #pragma unroll
  for (int t = 0; t < TM; ++t) {
    int n = nb + nodeg * TM + t;
    xbase[t] = in_ + (size_t)(n < N ? n : N - 1) * K;  // clamp: discard at store
  }
  const float4 bv = *(const float4*)&b[4 * colq];
  float acc[TM][4];
  #pragma unroll
  for (int t = 0; t < TM; ++t) {
    acc[t][0] = bv.x; acc[t][1] = bv.y; acc[t][2] = bv.z; acc[t][3] = bv.w;
  }
  for (int ks = 0; ks < K; ks += KH) {
    if (ks) __syncthreads();
    for (int idx = tid; idx < M * KH; idx += 256) {
      int j = idx / KH, kk = idx % KH;
      Wl[kk * WP + j] = W[(size_t)j * K + ks + kk];
    }
    __syncthreads();
    for (int k2 = 0; k2 < KH; k2 += 4) {
      const float4 wv0 = *(const float4*)&Wl[(k2 + 0) * WP + 4 * colq];
      const float4 wv1 = *(const float4*)&Wl[(k2 + 1) * WP + 4 * colq];
      const float4 wv2 = *(const float4*)&Wl[(k2 + 2) * WP + 4 * colq];
      const float4 wv3 = *(const float4*)&Wl[(k2 + 3) * WP + 4 * colq];
      #pragma unroll
      for (int t = 0; t < TM; ++t) {
        const float4 xv = *(const float4*)(xbase[t] + ks + k2);
        acc[t][0] += xv.x * wv0.x + xv.y * wv1.x + xv.z * wv2.x + xv.w * wv3.x;
        acc[t][1] += xv.x * wv0.y + xv.y * wv1.y + xv.z * wv2.y + xv.w * wv3.y;
        acc[t][2] += xv.x * wv0.z + xv.y * wv1.z + xv.z * wv2.z + xv.w * wv3.z;
        acc[t][3] += xv.x * wv0.w + xv.y * wv1.w + xv.z * wv2.w + xv.w * wv3.w;
      }
    }
  }
  if constexpr (!SCORES) {
    float* op = (float*)out_;
    #pragma unroll
    for (int t = 0; t < TM; ++t) {
      int n = nb + nodeg * TM + t;
      if (n < N) {
        float4 v = make_float4(acc[t][0], acc[t][1], acc[t][2], acc[t][3]);
        if constexpr (RELU) {
          v.x = fmaxf(v.x, 0.f); v.y = fmaxf(v.y, 0.f);
          v.z = fmaxf(v.z, 0.f); v.w = fmaxf(v.w, 0.f);
        }
        *(float4*)&op[(size_t)n * M + 4 * colq] = v;
      }
    }
  } else {
    unsigned short* op = (unsigned short*)out_;
    const float4 vA = *(const float4*)&aA[4 * colq];
    const float4 vB = *(const float4*)&aB[4 * colq];
    #pragma unroll
    for (int t = 0; t < TM; ++t) {
      int n = nb + nodeg * TM + t;
      if (n < N) {
        ushort4 u;
        u.x = f2bf(acc[t][0]); u.y = f2bf(acc[t][1]);
        u.z = f2bf(acc[t][2]); u.w = f2bf(acc[t][3]);
        *(ushort4*)&op[(size_t)n * M + 4 * colq] = u;
      }
      float pa = acc[t][0] * vA.x + acc[t][1] * vA.y + acc[t][2] * vA.z + acc[t][3] * vA.w;
      float pb = acc[t][0] * vB.x + acc[t][1] * vB.y + acc[t][2] * vB.z + acc[t][3] * vB.w;
      pa += __shfl_xor(pa, 1); pa += __shfl_xor(pa, 2);
      pb += __shfl_xor(pb, 1); pb += __shfl_xor(pb, 2);
      if ((colq & 3) == 0 && n < N) {
        oA[(size_t)n * 8 + (colq >> 2)] = pa;
        oB[(size_t)n * 8 + (colq >> 2)] = pb;
      }
    }
  }
}

// ---------------- stream encoder: LSTM(1 step) + concat staged, then dense 48->128 ----------------
__global__ __launch_bounds__(256) void enc_stream2_kernel(
    const float* __restrict__ xs,
    const float* __restrict__ W_ih,
    const float* __restrict__ b_ih,
    const float* __restrict__ b_hh,
    const float* __restrict__ scW,
    const float* __restrict__ scb,
    float* __restrict__ out, int N)
{
  constexpr int K = 48, M = 128, BN = 128;
  constexpr int COLG = M / 4, NODEG = 256 / COLG, TM = BN / NODEG, WP = M + 4;
  __shared__ float Wl[K * WP];
  __shared__ float xl[BN * K];
  const int tid = threadIdx.x;
  for (int idx = tid; idx < M * K; idx += 256) {
    int j = idx / K, k = idx % K;
    Wl[k * WP + j] = scW[idx];
  }
  const int nb = blockIdx.x * BN;
  for (int idx = tid; idx < BN * 16; idx += 256) {
    int n = idx >> 4, f = idx & 15;
    xl[n * K + f] = (nb + n < N) ? xs[(size_t)(nb + n) * 17 + f] : 0.f;
  }
  for (int idx = tid; idx < BN * 32; idx += 256) {
    int n = idx >> 5, jj = idx & 31;
    float h = 0.f;
    if (nb + n < N) {
      float xr = xs[(size_t)(nb + n) * 17 + 16];
      float gi = xr * W_ih[jj]      + b_ih[jj]      + b_hh[jj];
      float gg = xr * W_ih[64 + jj] + b_ih[64 + jj] + b_hh[64 + jj];
      float go = xr * W_ih[96 + jj] + b_ih[96 + jj] + b_hh[96 + jj];
      float c = sigm(gi) * tanhf(gg);
      h = sigm(go) * tanhf(c);
    }
    xl[n * K + 16 + jj] = h;
  }
  __syncthreads();
  const int colq = tid % COLG;
  const int nodeg = tid / COLG;
  const float4 bv = *(const float4*)&scb[4 * colq];
  float acc[TM][4];
  #pragma unroll
  for (int t = 0; t < TM; ++t) {
    acc[t][0] = bv.x; acc[t][1] = bv.y; acc[t][2] = bv.z; acc[t][3] = bv.w;
  }
  for (int k = 0; k < K; k += 4) {
    const float4 wv0 = *(const float4*)&Wl[(k + 0) * WP + 4 * colq];
    const float4 wv1 = *(const float4*)&Wl[(k + 1) * WP + 4 * colq];
    const float4 wv2 = *(const float4*)&Wl[(k + 2) * WP + 4 * colq];
    const float4 wv3 = *(const float4*)&Wl[(k + 3) * WP + 4 * colq];
    #pragma unroll
    for (int t = 0; t < TM; ++t) {
      const float4 xv = *(const float4*)&xl[(nodeg * TM + t) * K + k];
      acc[t][0] += xv.x * wv0.x + xv.y * wv1.x + xv.z * wv2.x + xv.w * wv3.x;
      acc[t][1] += xv.x * wv0.y + xv.y * wv1.y + xv.z * wv2.y + xv.w * wv3.y;
      acc[t][2] += xv.x * wv0.z + xv.y * wv1.z + xv.z * wv2.z + xv.w * wv3.z;
      acc[t][3] += xv.x * wv0.w + xv.y * wv1.w + xv.z * wv2.w + xv.w * wv3.w;
    }
  }
  #pragma unroll
  for (int t = 0; t < TM; ++t) {
    int n = nb + nodeg * TM + t;
    if (n < N) {
      float4 v = make_float4(fmaxf(acc[t][0], 0.f), fmaxf(acc[t][1], 0.f),
                             fmaxf(acc[t][2], 0.f), fmaxf(acc[t][3], 0.f));
      *(float4*)&out[(size_t)n * M + 4 * colq] = v;
    }
  }
}

// ---------------- fused segment-softmax + aggregation v4: bf16 gather, both edge types ----------------
#define CAP 128
__global__ __launch_bounds__(256) void att_agg4_kernel(
    const int* __restrict__ rp0, const int* __restrict__ dg0, const int* __restrict__ csr0,
    const float* __restrict__ asrc0, const float* __restrict__ adst0,
    const unsigned short* __restrict__ x0, float* __restrict__ o0,
    const int* __restrict__ rp1, const int* __restrict__ dg1, const int* __restrict__ csr1,
    const float* __restrict__ asrc1, const float* __restrict__ adst1,
    const unsigned short* __restrict__ x1, float* __restrict__ o1, int n_dst)
{
  const int y = blockIdx.y;
  const int* rp    = y ? rp1 : rp0;
  const int* dgs   = y ? dg1 : dg0;
  const int* csr   = y ? csr1 : csr0;
  const float* a_src = y ? asrc1 : asrc0;
  const float* a_dst = y ? adst1 : adst0;
  const uint32_t* xr = (const uint32_t*)(y ? x1 : x0);   // 64 uints (=128 bf16) per row
  float* out       = y ? o1 : o0;

  __shared__ float wexp[4][8][CAP + 4];   // [wave][head][edge], pitch 132: conflict-free
  __shared__ int   sidx[4][CAP];
  const int lane = threadIdx.x & 63;
  const int w = threadIdx.x >> 6;
  const int dst = blockIdx.x * 4 + w;
  if (dst >= n_dst) return;
  const int start = rp[dst];
  const int deg = dgs[dst];
  const int dcap = deg < CAP ? deg : CAP;
  float ad[8];
  {
    const float4* p = (const float4*)(a_dst + (size_t)dst * 8);
    float4 a0 = p[0], a1 = p[1];
    ad[0]=a0.x; ad[1]=a0.y; ad[2]=a0.z; ad[3]=a0.w;
    ad[4]=a1.x; ad[5]=a1.y; ad[6]=a1.z; ad[7]=a1.w;
  }
  float mh[8];
  #pragma unroll
  for (int h = 0; h < 8; ++h) mh[h] = -3.0e38f;
  for (int jj = lane; jj < dcap; jj += 64) {
    int s = csr[start + jj];
    sidx[w][jj] = s;
    const float4* p = (const float4*)(a_src + (size_t)s * 8);
    float4 a0 = p[0], a1 = p[1];
    float lg[8] = {a0.x+ad[0], a0.y+ad[1], a0.z+ad[2], a0.w+ad[3],
                   a1.x+ad[4], a1.y+ad[5], a1.z+ad[6], a1.w+ad[7]};
    #pragma unroll
    for (int h = 0; h < 8; ++h) {
      float v = lg[h];
      v = (v >= 0.f) ? v : 0.2f * v;
      wexp[w][h][jj] = v;
      mh[h] = fmaxf(mh[h], v);
    }
  }
  for (int jj = CAP + lane; jj < deg; jj += 64) {   // overflow (cold path)
    int s = csr[start + jj];
    const float4* p = (const float4*)(a_src + (size_t)s * 8);
    float4 a0 = p[0], a1 = p[1];
    float lg[8] = {a0.x+ad[0], a0.y+ad[1], a0.z+ad[2], a0.w+ad[3],
                   a1.x+ad[4], a1.y+ad[5], a1.z+ad[6], a1.w+ad[7]};
    #pragma unroll
    for (int h = 0; h < 8; ++h) {
      float v = lg[h];
      v = (v >= 0.f) ? v : 0.2f * v;
      mh[h] = fmaxf(mh[h], v);
    }
  }
  #pragma unroll
  for (int off = 32; off; off >>= 1)
    #pragma unroll
    for (int h = 0; h < 8; ++h) mh[h] = fmaxf(mh[h], __shfl_xor(mh[h], off));
  float sh[8] = {0,0,0,0,0,0,0,0};
  for (int jj = lane; jj < dcap; jj += 64) {
    #pragma unroll
    for (int h = 0; h < 8; ++h) {
      float e = __expf(wexp[w][h][jj] - mh[h]);
      wexp[w][h][jj] = e;
      sh[h] += e;
    }
  }
  for (int jj = CAP + lane; jj < deg; jj += 64) {   // overflow
    int s = csr[start + jj];
    const float4* p = (const float4*)(a_src + (size_t)s * 8);
    float4 a0 = p[0], a1 = p[1];
    float lg[8] = {a0.x+ad[0], a0.y+ad[1], a0.z+ad[2], a0.w+ad[3],
                   a1.x+ad[4], a1.y+ad[5], a1.z+ad[6], a1.w+ad[7]};
    #pragma unroll
    for (int h = 0; h < 8; ++h) {
      float v = lg[h];
      v = (v >= 0.f) ? v : 0.2f * v;
      sh[h] += __expf(v - mh[h]);
    }
  }
  #pragma unroll
  for (int off = 32; off; off >>= 1)
    #pragma unroll
    for (int h = 0; h < 8; ++h) sh[h] += __shfl_xor(sh[h], off);
  const int hh = lane >> 3;
  const float invh = 1.f / (sel8(sh, hh) + 1e-16f);
  const float mhh = sel8(mh, hh);
  const float adh = sel8(ad, hh);
  // pass 3: unnormalized weighted sum over bf16 rows (1 uint = 2 cols per lane), unroll x4
  float ax0 = 0.f, ay0 = 0.f, ax1 = 0.f, ay1 = 0.f;
  int jj = 0;
  for (; jj + 4 <= dcap; jj += 4) {
    int s0 = sidx[w][jj], s1 = sidx[w][jj+1], s2 = sidx[w][jj+2], s3 = sidx[w][jj+3];
    float w0 = wexp[w][hh][jj], w1 = wexp[w][hh][jj+1];
    float w2 = wexp[w][hh][jj+2], w3 = wexp[w][hh][jj+3];
    uint32_t v0 = xr[(size_t)s0 * 64 + lane];
    uint32_t v1 = xr[(size_t)s1 * 64 + lane];
    uint32_t v2 = xr[(size_t)s2 * 64 + lane];
    uint32_t v3 = xr[(size_t)s3 * 64 + lane];
    ax0 += w0 * __uint_as_float(v0 << 16) + w1 * __uint_as_float(v1 << 16);
    ay0 += w0 * __uint_as_float(v0 & 0xffff0000u) + w1 * __uint_as_float(v1 & 0xffff0000u);
    ax1 += w2 * __uint_as_float(v2 << 16) + w3 * __uint_as_float(v3 << 16);
    ay1 += w2 * __uint_as_float(v2 & 0xffff0000u) + w3 * __uint_as_float(v3 & 0xffff0000u);
  }
  for (; jj < dcap; ++jj) {
    int s0 = sidx[w][jj];
    float w0 = wexp[w][hh][jj];
    uint32_t v0 = xr[(size_t)s0 * 64 + lane];
    ax0 += w0 * __uint_as_float(v0 << 16);
    ay0 += w0 * __uint_as_float(v0 & 0xffff0000u);
  }
  for (jj = CAP; jj < deg; ++jj) {   // overflow
    int s = csr[start + jj];
    float v = a_src[(size_t)s * 8 + hh] + adh;
    v = (v >= 0.f) ? v : 0.2f * v;
    float w0 = __expf(v - mhh);
    uint32_t v0 = xr[(size_t)s * 64 + lane];
    ax0 += w0 * __uint_as_float(v0 << 16);
    ay0 += w0 * __uint_as_float(v0 & 0xffff0000u);
  }
  float2 o = make_float2(fmaxf((ax0 + ax1) * invh, 0.f), fmaxf((ay0 + ay1) * invh, 0.f));
  *(float2*)&out[(size_t)dst * 128 + lane * 2] = o;
}

// ---------------- fused output head MLP: out = W2·relu(W1·h + b1) + b2, dual dispatch ----------------
__global__ __launch_bounds__(256) void headmlp_kernel(
    const float* __restrict__ h0, const float* __restrict__ h1,
    const float* __restrict__ W1, const float* __restrict__ b1,
    const float* __restrict__ W2, const float* __restrict__ b2,
    float* __restrict__ out, int N)
{
  constexpr int K = 128, M = 64, BN = 64, KH = 64;
  constexpr int COLG = M / 4, NODEG = 256 / COLG, TM = BN / NODEG, WP = M + 4; // 16,16,4,68
  const int y = blockIdx.y;
  const float* in_ = y ? h1 : h0;
  const float* W1p = W1 + (size_t)y * 64 * 128;
  const float* b1p = b1 + y * 64;
  const float* W2p = W2 + (size_t)y * 64 * 64;
  const float* b2p = b2 + y * 64;
  float* outp = out + (size_t)y * N * 64;

  __shared__ float Wl[KH * WP];
  __shared__ float zl[BN * WP];
  const int tid = threadIdx.x;
  const int colq = tid % COLG;
  const int nodeg = tid / COLG;
  const int nb = blockIdx.x * BN;
  const float* xbase[TM];
  #pragma unroll
  for (int t = 0; t < TM; ++t) {
    int n = nb + nodeg * TM + t;
    xbase[t] = in_ + (size_t)(n < N ? n : N - 1) * K;
  }
  const float4 b1v = *(const float4*)&b1p[4 * colq];
  float acc[TM][4];
  #pragma unroll
  for (int t = 0; t < TM; ++t) {
    acc[t][0] = b1v.x; acc[t][1] = b1v.y; acc[t][2] = b1v.z; acc[t][3] = b1v.w;
  }
  for (int ks = 0; ks < K; ks += KH) {
    if (ks) __syncthreads();
    for (int idx = tid; idx < M * KH; idx += 256) {
      int j = idx / KH, kk = idx % KH;
      Wl[kk * WP + j] = W1p[(size_t)j * K + ks + kk];
    }
    __syncthreads();
    for (int k2 = 0; k2 < KH; k2 += 4) {
      const float4 wv0 = *(const float4*)&Wl[(k2 + 0) * WP + 4 * colq];
      const float4 wv1 = *(const float4*)&Wl[(k2 + 1) * WP + 4 * colq];
      const float4 wv2 = *(const float4*)&Wl[(k2 + 2) * WP + 4 * colq];
      const float4 wv3 = *(const float4*)&Wl[(k2 + 3) * WP + 4 * colq];
      #pragma unroll
      for (int t = 0; t < TM; ++t) {
        const float4 xv = *(const float4*)(xbase[t] + ks + k2);
        acc[t][0] += xv.x * wv0.x + xv.y * wv1.x + xv.z * wv2.x + xv.w * wv3.x;
        acc[t][1] += xv.x * wv0.y + xv.y * wv1.y + xv.z * wv2.y + xv.w * wv3.y;
        acc[t][2] += xv.x * wv0.z + xv.y * wv1.z + xv.z * wv2.z + xv.w * wv3.z;
        acc[t][3] += xv.x * wv0.w + xv.y * wv1.w + xv.z * wv2.w + xv.w * wv3.w;
      }
    }
  }
  // z = relu(acc) -> LDS
  #pragma unroll
  for (int t = 0; t < TM; ++t) {
    float4 z = make_float4(fmaxf(acc[t][0], 0.f), fmaxf(acc[t][1], 0.f),
                           fmaxf(acc[t][2], 0.f), fmaxf(acc[t][3], 0.f));
    *(float4*)&zl[(nodeg * TM + t) * WP + 4 * colq] = z;
  }
  __syncthreads();
  // restage Wl with W2 (64x64)
  for (int idx = tid; idx < 64 * 64; idx += 256) {
    int j = idx >> 6, kk = idx & 63;
    Wl[kk * WP + j] = W2p[idx];
  }
  __syncthreads();
  const float4 b2v = *(const float4*)&b2p[4 * colq];
  float acc2[TM][4];
  #pragma unroll
  for (int t = 0; t < TM; ++t) {
    acc2[t][0] = b2v.x; acc2[t][1] = b2v.y; acc2[t][2] = b2v.z; acc2[t][3] = b2v.w;
  }
  for (int k2 = 0; k2 < 64; k2 += 4) {
    const float4 wv0 = *(const float4*)&Wl[(k2 + 0) * WP + 4 * colq];
    const float4 wv1 = *(const float4*)&Wl[(k2 + 1) * WP + 4 * colq];
    const float4 wv2 = *(const float4*)&Wl[(k2 + 2) * WP + 4 * colq];
    const float4 wv3 = *(const float4*)&Wl[(k2 + 3) * WP + 4 * colq];
    #pragma unroll
    for (int t = 0; t < TM; ++t) {
      const float4 xv = *(const float4*)&zl[(nodeg * TM + t) * WP + k2];
      acc2[t][0] += xv.x * wv0.x + xv.y * wv1.x + xv.z * wv2.x + xv.w * wv3.x;
      acc2[t][1] += xv.x * wv0.y + xv.y * wv1.y + xv.z * wv2.y + xv.w * wv3.y;
      acc2[t][2] += xv.x * wv0.z + xv.y * wv1.z + xv.z * wv2.z + xv.w * wv3.z;
      acc2[t][3] += xv.x * wv0.w + xv.y * wv1.w + xv.z * wv2.w + xv.w * wv3.w;
    }
  }
  #pragma unroll
  for (int t = 0; t < TM; ++t) {
    int n = nb + nodeg * TM + t;
    if (n < N) {
      *(float4*)&outp[(size_t)n * M + 4 * colq] =
          make_float4(acc2[t][0], acc2[t][1], acc2[t][2], acc2[t][3]);
    }
  }
}

// ---------------- launch ----------------
extern "C" void kernel_launch(void* const* d_in, const int* in_sizes, int n_in,
                              void* d_out, int out_size, void* d_ws, size_t ws_size,
                              hipStream_t stream) {
  (void)in_sizes; (void)n_in; (void)out_size; (void)ws_size;
  const float* x_stream  = (const float*)d_in[0];
  const float* x_device  = (const float*)d_in[1];
  const int*   edge_sd   = (const int*)d_in[2];
  const int*   edge_ds   = (const int*)d_in[3];
  const float* lstm_W_ih = (const float*)d_in[4];
  const float* lstm_b_ih = (const float*)d_in[5];
  const float* lstm_b_hh = (const float*)d_in[6];
  const float* sc_W      = (const float*)d_in[7];
  const float* sc_b      = (const float*)d_in[8];
  const float* dev_W     = (const float*)d_in[9];
  const float* dev_b     = (const float*)d_in[10];
  const float* proj_W    = (const float*)d_in[11];
  const float* proj_b    = (const float*)d_in[12];
  const float* att_src   = (const float*)d_in[13];
  const float* att_dst   = (const float*)d_in[14];
  // d_in[15..17] = q, k_W, k_b — mathematically unused (softmax over singleton stack)
  const float* outp_W1   = (const float*)d_in[18];
  const float* outp_b1   = (const float*)d_in[19];
  const float* outp_W2   = (const float*)d_in[20];
  const float* outp_b2   = (const float*)d_in[21];
  float* out_f = (float*)d_out;

  float* ws = (float*)d_ws;
  size_t off = 0;
  float* h0  = ws + off; off += (size_t)NS_N * 128;
  float* h1  = ws + off; off += (size_t)ND_N * 128;
  unsigned short* xb0 = (unsigned short*)(ws + off); off += (size_t)NS_N * 64;  // bf16 128/node
  unsigned short* xb1 = (unsigned short*)(ws + off); off += (size_t)ND_N * 64;
  float* as0 = ws + off; off += (size_t)NS_N * 8;
  float* ad0 = ws + off; off += (size_t)NS_N * 8;
  float* as1 = ws + off; off += (size_t)ND_N * 8;
  float* ad1 = ws + off; off += (size_t)ND_N * 8;
  int* ip = (int*)(ws + off);
  int* cnt    = ip; ip += ND_N + NS_N;       // [cnt_sd | cnt_ds]  (zeroed)
  int* totals = ip; ip += 2;                 // (zeroed, contiguous with cnt)
  int* rp     = ip; ip += ND_N + NS_N;       // [rp_sd | rp_ds]
  int* cur    = ip; ip += ND_N + NS_N;       // fill cursors
  int* csr_sd = ip; ip += E_N;
  int* csr_ds = ip; ip += E_N;

  hipMemsetAsync(cnt, 0, (size_t)(ND_N + NS_N + 2) * sizeof(int), stream);

  const int EB = (E_N + 255) / 256;
  count2_kernel<<<EB, 256, 0, stream>>>(edge_sd + E_N, edge_ds + E_N, cnt, E_N);
  alloc_kernel<<<dim3((50000 + 255) / 256, 2), 256, 0, stream>>>(cnt, rp, cur, totals, 50000);
  fill2_kernel<<<dim3(EB, 2), 256, 0, stream>>>(edge_sd, edge_ds, cur, csr_sd, csr_ds, E_N);

  const int GB64 = (NS_N + 63) / 64;    // 782
  const int GB128 = (NS_N + 127) / 128; // 391

  enc_stream2_kernel<<<GB128, 256, 0, stream>>>(
      x_stream, lstm_W_ih, lstm_b_ih, lstm_b_hh, sc_W, sc_b, h0, NS_N);
  dense6_kernel<32, 128, 64, true, false, false><<<GB64, 256, 0, stream>>>(
      x_device, dev_W, dev_b, h1, nullptr, nullptr, nullptr, nullptr,
      nullptr, nullptr, nullptr, nullptr, nullptr, nullptr, nullptr, nullptr, ND_N);

  for (int l = 0; l < 2; ++l) {
    // dual projection + fused attention scores; output bf16 gather payload
    dense6_kernel<128, 128, 64, false, true, true><<<dim3(GB64, 2), 256, 0, stream>>>(
        h0, proj_W + (size_t)(l * 2 + 0) * 16384, proj_b + (l * 2 + 0) * 128, xb0,
        att_src + (l * 2 + 0) * 128, att_dst + (l * 2 + 1) * 128, as0, ad0,
        h1, proj_W + (size_t)(l * 2 + 1) * 16384, proj_b + (l * 2 + 1) * 128, xb1,
        att_src + (l * 2 + 1) * 128, att_dst + (l * 2 + 0) * 128, as1, ad1, NS_N);
    // fused aggregation for both edge types (bf16 gather)
    att_agg4_kernel<<<dim3((ND_N + 3) / 4, 2), 256, 0, stream>>>(
        rp, cnt, csr_sd, as0, ad1, xb0, h1,
        rp + 50000, cnt + 50000, csr_ds, as1, ad0, xb1, h0, ND_N);
  }

  // fused output heads (both types)
  headmlp_kernel<<<dim3(GB64, 2), 256, 0, stream>>>(
      h0, h1, outp_W1, outp_b1, outp_W2, outp_b2, out_f, NS_N);
}

// Round 7
// 538.697 us; speedup vs baseline: 3.5065x; 1.2038x over previous
//
#include <hip/hip_runtime.h>
#include <hip/hip_bf16.h>
#include <cstdint>

static constexpr int NS_N = 50000;
static constexpr int ND_N = 50000;
static constexpr int E_N  = 500000;

__device__ __forceinline__ float sigm(float x) { return 1.f / (1.f + __expf(-x)); }

__device__ __forceinline__ unsigned short f2bf(float f) {
  __hip_bfloat16 h = __float2bfloat16(f);   // RTNE
  return *reinterpret_cast<unsigned short*>(&h);
}

// ---------------- CSR build (scan-free) ----------------
__global__ void count2_kernel(const int* __restrict__ dsd, const int* __restrict__ dds,
                              int* __restrict__ cnt, int n) {
  int i = blockIdx.x * blockDim.x + threadIdx.x;
  if (i < n) {
    atomicAdd(&cnt[dsd[i]], 1);
    atomicAdd(&cnt[ND_N + dds[i]], 1);
  }
}

// wave-level bump allocation: rp[i] = start offset; cur[i] = running cursor for fill
__global__ void alloc_kernel(const int* __restrict__ cnt, int* __restrict__ rp,
                             int* __restrict__ cur, int* __restrict__ totals, int n) {
  const int y = blockIdx.y;
  const int* c = cnt + (size_t)y * n;
  int* r = rp + (size_t)y * n;
  int* q = cur + (size_t)y * n;
  const int i = blockIdx.x * 256 + threadIdx.x;
  const int lane = threadIdx.x & 63;
  int v = (i < n) ? c[i] : 0;
  int incl = v;
  #pragma unroll
  for (int off = 1; off < 64; off <<= 1) {
    int t = __shfl_up(incl, off);
    if (lane >= off) incl += t;
  }
  int tot = __shfl(incl, 63);
  int base = 0;
  if (lane == 0) base = atomicAdd(&totals[y], tot);
  base = __shfl(base, 0);
  if (i < n) {
    int st = base + incl - v;
    r[i] = st;
    q[i] = st;
  }
}

__global__ void fill2_kernel(const int* __restrict__ e_sd, const int* __restrict__ e_ds,
                             int* __restrict__ cur,
                             int* __restrict__ csr_sd, int* __restrict__ csr_ds, int n) {
  const int y = blockIdx.y;
  const int* e = y ? e_ds : e_sd;
  int* csr = y ? csr_ds : csr_sd;
  int* q = cur + (size_t)y * 50000;
  int i = blockIdx.x * blockDim.x + threadIdx.x;
  if (i < n) {
    int d = e[E_N + i];
    int pos = atomicAdd(&q[d], 1);
    csr[pos] = e[i];
  }
}

// ---------------- dense6: register-tiled f32 GEMM, K-split LDS staging, dual dispatch ----------------
// SCORES mode: writes bf16 output + per-head attention scores (no f32 output).
template<int K, int M, int BN, bool RELU, bool SCORES, bool DUAL>
__global__ __launch_bounds__(256) void dense6_kernel(
    const float* __restrict__ in0, const float* __restrict__ W0,
    const float* __restrict__ b0, void* __restrict__ out0,
    const float* __restrict__ aA0, const float* __restrict__ aB0,
    float* __restrict__ oA0, float* __restrict__ oB0,
    const float* __restrict__ in1, const float* __restrict__ W1x,
    const float* __restrict__ b1x, void* __restrict__ out1,
    const float* __restrict__ aA1, const float* __restrict__ aB1,
    float* __restrict__ oA1, float* __restrict__ oB1, int N)
{
  static_assert(M % 4 == 0 && K % 4 == 0, "");
  constexpr int KH = (K > 64) ? 64 : K;
  constexpr int COLG = M / 4;
  constexpr int NODEG = 256 / COLG;
  constexpr int TM = BN / NODEG;
  constexpr int WP = M + 4;
  static_assert(BN % NODEG == 0 && 256 % COLG == 0 && K % KH == 0, "");
  const float* in_ = in0; const float* W = W0; const float* b = b0; void* out_ = out0;
  const float* aA = aA0; const float* aB = aB0; float* oA = oA0; float* oB = oB0;
  if constexpr (DUAL) {
    if (blockIdx.y) {
      in_ = in1; W = W1x; b = b1x; out_ = out1;
      aA = aA1; aB = aB1; oA = oA1; oB = oB1;
    }
  }
  __shared__ float Wl[KH * WP];
  const int tid = threadIdx.x;
  const int colq = tid % COLG;
  const int nodeg = tid / COLG;
  const int nb = blockIdx.x * BN;
  const float* xbase[TM];
  #pragma unroll
  for (int t = 0; t < TM; ++t) {
    int n = nb + nodeg * TM + t;
    xbase[t] = in_ + (size_t)(n < N ? n : N - 1) * K;  // clamp: discard at store
  }
  const float4 bv = *(const float4*)&b[4 * colq];
  float acc[TM][4];
  #pragma unroll
  for (int t = 0; t < TM; ++t) {
    acc[t][0] = bv.x; acc[t][1] = bv.y; acc[t][2] = bv.z; acc[t][3] = bv.w;
  }
  for (int ks = 0; ks < K; ks += KH) {
    if (ks) __syncthreads();
    for (int idx = tid; idx < M * KH; idx += 256) {
      int j = idx / KH, kk = idx % KH;
      Wl[kk * WP + j] = W[(size_t)j * K + ks + kk];
    }
    __syncthreads();
    for (int k2 = 0; k2 < KH; k2 += 4) {
      const float4 wv0 = *(const float4*)&Wl[(k2 + 0) * WP + 4 * colq];
      const float4 wv1 = *(const float4*)&Wl[(k2 + 1) * WP + 4 * colq];
      const float4 wv2 = *(const float4*)&Wl[(k2 + 2) * WP + 4 * colq];
      const float4 wv3 = *(const float4*)&Wl[(k2 + 3) * WP + 4 * colq];
      #pragma unroll
      for (int t = 0; t < TM; ++t) {
        const float4 xv = *(const float4*)(xbase[t] + ks + k2);
        acc[t][0] += xv.x * wv0.x + xv.y * wv1.x + xv.z * wv2.x + xv.w * wv3.x;
        acc[t][1] += xv.x * wv0.y + xv.y * wv1.y + xv.z * wv2.y + xv.w * wv3.y;
        acc[t][2] += xv.x * wv0.z + xv.y * wv1.z + xv.z * wv2.z + xv.w * wv3.z;
        acc[t][3] += xv.x * wv0.w + xv.y * wv1.w + xv.z * wv2.w + xv.w * wv3.w;
      }
    }
  }
  if constexpr (!SCORES) {
    float* op = (float*)out_;
    #pragma unroll
    for (int t = 0; t < TM; ++t) {
      int n = nb + nodeg * TM + t;
      if (n < N) {
        float4 v = make_float4(acc[t][0], acc[t][1], acc[t][2], acc[t][3]);
        if constexpr (RELU) {
          v.x = fmaxf(v.x, 0.f); v.y = fmaxf(v.y, 0.f);
          v.z = fmaxf(v.z, 0.f); v.w = fmaxf(v.w, 0.f);
        }
        *(float4*)&op[(size_t)n * M + 4 * colq] = v;
      }
    }
  } else {
    unsigned short* op = (unsigned short*)out_;
    const float4 vA = *(const float4*)&aA[4 * colq];
    const float4 vB = *(const float4*)&aB[4 * colq];
    #pragma unroll
    for (int t = 0; t < TM; ++t) {
      int n = nb + nodeg * TM + t;
      if (n < N) {
        ushort4 u;
        u.x = f2bf(acc[t][0]); u.y = f2bf(acc[t][1]);
        u.z = f2bf(acc[t][2]); u.w = f2bf(acc[t][3]);
        *(ushort4*)&op[(size_t)n * M + 4 * colq] = u;
      }
      float pa = acc[t][0] * vA.x + acc[t][1] * vA.y + acc[t][2] * vA.z + acc[t][3] * vA.w;
      float pb = acc[t][0] * vB.x + acc[t][1] * vB.y + acc[t][2] * vB.z + acc[t][3] * vB.w;
      pa += __shfl_xor(pa, 1); pa += __shfl_xor(pa, 2);
      pb += __shfl_xor(pb, 1); pb += __shfl_xor(pb, 2);
      if ((colq & 3) == 0 && n < N) {
        oA[(size_t)n * 8 + (colq >> 2)] = pa;
        oB[(size_t)n * 8 + (colq >> 2)] = pb;
      }
    }
  }
}

// ---------------- fused encoders: y=0 stream LSTM+dense48->128, y=1 device dense32->128 ----------------
__global__ __launch_bounds__(256) void enc_fused_kernel(
    const float* __restrict__ xs,
    const float* __restrict__ W_ih, const float* __restrict__ b_ih,
    const float* __restrict__ b_hh,
    const float* __restrict__ scW, const float* __restrict__ scb,
    float* __restrict__ h0out,
    const float* __restrict__ xd,
    const float* __restrict__ devW, const float* __restrict__ devb,
    float* __restrict__ h1out, int N)
{
  __shared__ float smem[9408];
  const int tid = threadIdx.x;
  constexpr int M = 128, BN = 64, WP = M + 4;
  constexpr int COLG = 32, TM = 8;          // NODEG = 8
  const int colq = tid % COLG;
  const int nodeg = tid / COLG;
  const int nb = blockIdx.x * BN;

  if (blockIdx.y == 0) {
    // ---- stream encoder ----
    constexpr int K = 48;
    float* Wl = smem;             // 48*132 = 6336
    float* xl = smem + 6336;      // 64*48  = 3072
    for (int idx = tid; idx < M * K; idx += 256) {
      int j = idx / K, k = idx % K;
      Wl[k * WP + j] = scW[idx];
    }
    for (int idx = tid; idx < BN * 16; idx += 256) {
      int n = idx >> 4, f = idx & 15;
      xl[n * K + f] = (nb + n < N) ? xs[(size_t)(nb + n) * 17 + f] : 0.f;
    }
    for (int idx = tid; idx < BN * 32; idx += 256) {
      int n = idx >> 5, jj = idx & 31;
      float h = 0.f;
      if (nb + n < N) {
        float xr = xs[(size_t)(nb + n) * 17 + 16];
        float gi = xr * W_ih[jj]      + b_ih[jj]      + b_hh[jj];
        float gg = xr * W_ih[64 + jj] + b_ih[64 + jj] + b_hh[64 + jj];
        float go = xr * W_ih[96 + jj] + b_ih[96 + jj] + b_hh[96 + jj];
        float c = sigm(gi) * tanhf(gg);
        h = sigm(go) * tanhf(c);
      }
      xl[n * K + 16 + jj] = h;
    }
    __syncthreads();
    const float4 bv = *(const float4*)&scb[4 * colq];
    float acc[TM][4];
    #pragma unroll
    for (int t = 0; t < TM; ++t) {
      acc[t][0] = bv.x; acc[t][1] = bv.y; acc[t][2] = bv.z; acc[t][3] = bv.w;
    }
    for (int k = 0; k < K; k += 4) {
      const float4 wv0 = *(const float4*)&Wl[(k + 0) * WP + 4 * colq];
      const float4 wv1 = *(const float4*)&Wl[(k + 1) * WP + 4 * colq];
      const float4 wv2 = *(const float4*)&Wl[(k + 2) * WP + 4 * colq];
      const float4 wv3 = *(const float4*)&Wl[(k + 3) * WP + 4 * colq];
      #pragma unroll
      for (int t = 0; t < TM; ++t) {
        const float4 xv = *(const float4*)&xl[(nodeg * TM + t) * K + k];
        acc[t][0] += xv.x * wv0.x + xv.y * wv1.x + xv.z * wv2.x + xv.w * wv3.x;
        acc[t][1] += xv.x * wv0.y + xv.y * wv1.y + xv.z * wv2.y + xv.w * wv3.y;
        acc[t][2] += xv.x * wv0.z + xv.y * wv1.z + xv.z * wv2.z + xv.w * wv3.z;
        acc[t][3] += xv.x * wv0.w + xv.y * wv1.w + xv.z * wv2.w + xv.w * wv3.w;
      }
    }
    #pragma unroll
    for (int t = 0; t < TM; ++t) {
      int n = nb + nodeg * TM + t;
      if (n < N) {
        *(float4*)&h0out[(size_t)n * M + 4 * colq] =
            make_float4(fmaxf(acc[t][0], 0.f), fmaxf(acc[t][1], 0.f),
                        fmaxf(acc[t][2], 0.f), fmaxf(acc[t][3], 0.f));
      }
    }
  } else {
    // ---- device encoder (K=32) ----
    constexpr int K = 32;
    float* Wl = smem;             // 32*132 = 4224
    for (int idx = tid; idx < M * K; idx += 256) {
      int j = idx / K, k = idx % K;
      Wl[k * WP + j] = devW[idx];
    }
    __syncthreads();
    const float* xbase[TM];
    #pragma unroll
    for (int t = 0; t < TM; ++t) {
      int n = nb + nodeg * TM + t;
      xbase[t] = xd + (size_t)(n < N ? n : N - 1) * K;
    }
    const float4 bv = *(const float4*)&devb[4 * colq];
    float acc[TM][4];
    #pragma unroll
    for (int t = 0; t < TM; ++t) {
      acc[t][0] = bv.x; acc[t][1] = bv.y; acc[t][2] = bv.z; acc[t][3] = bv.w;
    }
    for (int k = 0; k < K; k += 4) {
      const float4 wv0 = *(const float4*)&Wl[(k + 0) * WP + 4 * colq];
      const float4 wv1 = *(const float4*)&Wl[(k + 1) * WP + 4 * colq];
      const float4 wv2 = *(const float4*)&Wl[(k + 2) * WP + 4 * colq];
      const float4 wv3 = *(const float4*)&Wl[(k + 3) * WP + 4 * colq];
      #pragma unroll
      for (int t = 0; t < TM; ++t) {
        const float4 xv = *(const float4*)(xbase[t] + k);
        acc[t][0] += xv.x * wv0.x + xv.y * wv1.x + xv.z * wv2.x + xv.w * wv3.x;
        acc[t][1] += xv.x * wv0.y + xv.y * wv1.y + xv.z * wv2.y + xv.w * wv3.y;
        acc[t][2] += xv.x * wv0.z + xv.y * wv1.z + xv.z * wv2.z + xv.w * wv3.z;
        acc[t][3] += xv.x * wv0.w + xv.y * wv1.w + xv.z * wv2.w + xv.w * wv3.w;
      }
    }
    #pragma unroll
    for (int t = 0; t < TM; ++t) {
      int n = nb + nodeg * TM + t;
      if (n < N) {
        *(float4*)&h1out[(size_t)n * M + 4 * colq] =
            make_float4(fmaxf(acc[t][0], 0.f), fmaxf(acc[t][1], 0.f),
                        fmaxf(acc[t][2], 0.f), fmaxf(acc[t][3], 0.f));
      }
    }
  }
}

// ---------------- att_agg5: head-x-edge lane layout for scores, bf16 gather ----------------
// lane = h*8 + e: head h scores edges e, e+8, ... Reductions are 3 shfl_xor steps within
// the 8-lane head group. Pass-3 head (col/16 = lane>>3) coincides with h.
#define CAP 128
__global__ __launch_bounds__(256) void att_agg5_kernel(
    const int* __restrict__ rp0, const int* __restrict__ dg0, const int* __restrict__ csr0,
    const float* __restrict__ asrc0, const float* __restrict__ adst0,
    const unsigned short* __restrict__ x0, float* __restrict__ o0,
    const int* __restrict__ rp1, const int* __restrict__ dg1, const int* __restrict__ csr1,
    const float* __restrict__ asrc1, const float* __restrict__ adst1,
    const unsigned short* __restrict__ x1, float* __restrict__ o1, int n_dst)
{
  const int y = blockIdx.y;
  const int* rp      = y ? rp1 : rp0;
  const int* dgs     = y ? dg1 : dg0;
  const int* csr     = y ? csr1 : csr0;
  const float* a_src = y ? asrc1 : asrc0;
  const float* a_dst = y ? adst1 : adst0;
  const uint32_t* xr = (const uint32_t*)(y ? x1 : x0);   // 64 uints (=128 bf16) per row
  float* out         = y ? o1 : o0;

  __shared__ float wexp[4][8][CAP + 4];   // [wave][head][edge], pitch 132
  __shared__ int   sidx[4][CAP];
  const int lane = threadIdx.x & 63;
  const int w = threadIdx.x >> 6;
  const int h = lane >> 3;   // head (same for score + agg phases)
  const int e = lane & 7;    // edge slot within score phase
  const int dst = blockIdx.x * 4 + w;
  if (dst >= n_dst) return;
  const int start = rp[dst];
  const int deg = dgs[dst];
  const int dcap = deg < CAP ? deg : CAP;
  const float adh = a_dst[(size_t)dst * 8 + h];

  // pass 1: logits + per-head max (all 64 lanes active: 8 heads x 8 edges)
  float m = -3.0e38f;
  for (int jj = e; jj < deg; jj += 8) {
    int s = csr[start + jj];
    float v = a_src[(size_t)s * 8 + h] + adh;
    v = (v >= 0.f) ? v : 0.2f * v;
    if (jj < CAP) {
      wexp[w][h][jj] = v;
      if (h == 0) sidx[w][jj] = s;
    }
    m = fmaxf(m, v);
  }
  m = fmaxf(m, __shfl_xor(m, 1));
  m = fmaxf(m, __shfl_xor(m, 2));
  m = fmaxf(m, __shfl_xor(m, 4));

  // pass 2: exp + per-head sum
  float ssum = 0.f;
  for (int jj = e; jj < dcap; jj += 8) {
    float ev = __expf(wexp[w][h][jj] - m);
    wexp[w][h][jj] = ev;
    ssum += ev;
  }
  for (int jj = CAP + e; jj < deg; jj += 8) {   // overflow (cold path)
    int s = csr[start + jj];
    float v = a_src[(size_t)s * 8 + h] + adh;
    v = (v >= 0.f) ? v : 0.2f * v;
    ssum += __expf(v - m);
  }
  ssum += __shfl_xor(ssum, 1);
  ssum += __shfl_xor(ssum, 2);
  ssum += __shfl_xor(ssum, 4);
  const float invh = 1.f / (ssum + 1e-16f);

  // pass 3: unnormalized weighted sum over bf16 rows (1 uint = 2 cols per lane), unroll x4
  float ax0 = 0.f, ay0 = 0.f, ax1 = 0.f, ay1 = 0.f;
  int jj = 0;
  for (; jj + 4 <= dcap; jj += 4) {
    int s0 = sidx[w][jj], s1 = sidx[w][jj+1], s2 = sidx[w][jj+2], s3 = sidx[w][jj+3];
    float w0 = wexp[w][h][jj], w1 = wexp[w][h][jj+1];
    float w2 = wexp[w][h][jj+2], w3 = wexp[w][h][jj+3];
    uint32_t v0 = xr[(size_t)s0 * 64 + lane];
    uint32_t v1 = xr[(size_t)s1 * 64 + lane];
    uint32_t v2 = xr[(size_t)s2 * 64 + lane];
    uint32_t v3 = xr[(size_t)s3 * 64 + lane];
    ax0 += w0 * __uint_as_float(v0 << 16) + w1 * __uint_as_float(v1 << 16);
    ay0 += w0 * __uint_as_float(v0 & 0xffff0000u) + w1 * __uint_as_float(v1 & 0xffff0000u);
    ax1 += w2 * __uint_as_float(v2 << 16) + w3 * __uint_as_float(v3 << 16);
    ay1 += w2 * __uint_as_float(v2 & 0xffff0000u) + w3 * __uint_as_float(v3 & 0xffff0000u);
  }
  for (; jj < dcap; ++jj) {
    int s0 = sidx[w][jj];
    float w0 = wexp[w][h][jj];
    uint32_t v0 = xr[(size_t)s0 * 64 + lane];
    ax0 += w0 * __uint_as_float(v0 << 16);
    ay0 += w0 * __uint_as_float(v0 & 0xffff0000u);
  }
  for (jj = CAP; jj < deg; ++jj) {   // overflow
    int s = csr[start + jj];
    float v = a_src[(size_t)s * 8 + h] + adh;
    v = (v >= 0.f) ? v : 0.2f * v;
    float w0 = __expf(v - m);
    uint32_t v0 = xr[(size_t)s * 64 + lane];
    ax0 += w0 * __uint_as_float(v0 << 16);
    ay0 += w0 * __uint_as_float(v0 & 0xffff0000u);
  }
  float2 o = make_float2(fmaxf((ax0 + ax1) * invh, 0.f), fmaxf((ay0 + ay1) * invh, 0.f));
  *(float2*)&out[(size_t)dst * 128 + lane * 2] = o;
}

// ---------------- fused output head MLP: out = W2·relu(W1·h + b1) + b2, dual dispatch ----------------
__global__ __launch_bounds__(256) void headmlp_kernel(
    const float* __restrict__ h0, const float* __restrict__ h1,
    const float* __restrict__ W1, const float* __restrict__ b1,
    const float* __restrict__ W2, const float* __restrict__ b2,
    float* __restrict__ out, int N)
{
  constexpr int K = 128, M = 64, BN = 64, KH = 64;
  constexpr int COLG = M / 4, NODEG = 256 / COLG, TM = BN / NODEG, WP = M + 4; // 16,16,4,68
  const int y = blockIdx.y;
  const float* in_ = y ? h1 : h0;
  const float* W1p = W1 + (size_t)y * 64 * 128;
  const float* b1p = b1 + y * 64;
  const float* W2p = W2 + (size_t)y * 64 * 64;
  const float* b2p = b2 + y * 64;
  float* outp = out + (size_t)y * N * 64;

  __shared__ float Wl[KH * WP];
  __shared__ float zl[BN * WP];
  const int tid = threadIdx.x;
  const int colq = tid % COLG;
  const int nodeg = tid / COLG;
  const int nb = blockIdx.x * BN;
  const float* xbase[TM];
  #pragma unroll
  for (int t = 0; t < TM; ++t) {
    int n = nb + nodeg * TM + t;
    xbase[t] = in_ + (size_t)(n < N ? n : N - 1) * K;
  }
  const float4 b1v = *(const float4*)&b1p[4 * colq];
  float acc[TM][4];
  #pragma unroll
  for (int t = 0; t < TM; ++t) {
    acc[t][0] = b1v.x; acc[t][1] = b1v.y; acc[t][2] = b1v.z; acc[t][3] = b1v.w;
  }
  for (int ks = 0; ks < K; ks += KH) {
    if (ks) __syncthreads();
    for (int idx = tid; idx < M * KH; idx += 256) {
      int j = idx / KH, kk = idx % KH;
      Wl[kk * WP + j] = W1p[(size_t)j * K + ks + kk];
    }
    __syncthreads();
    for (int k2 = 0; k2 < KH; k2 += 4) {
      const float4 wv0 = *(const float4*)&Wl[(k2 + 0) * WP + 4 * colq];
      const float4 wv1 = *(const float4*)&Wl[(k2 + 1) * WP + 4 * colq];
      const float4 wv2 = *(const float4*)&Wl[(k2 + 2) * WP + 4 * colq];
      const float4 wv3 = *(const float4*)&Wl[(k2 + 3) * WP + 4 * colq];
      #pragma unroll
      for (int t = 0; t < TM; ++t) {
        const float4 xv = *(const float4*)(xbase[t] + ks + k2);
        acc[t][0] += xv.x * wv0.x + xv.y * wv1.x + xv.z * wv2.x + xv.w * wv3.x;
        acc[t][1] += xv.x * wv0.y + xv.y * wv1.y + xv.z * wv2.y + xv.w * wv3.y;
        acc[t][2] += xv.x * wv0.z + xv.y * wv1.z + xv.z * wv2.z + xv.w * wv3.z;
        acc[t][3] += xv.x * wv0.w + xv.y * wv1.w + xv.z * wv2.w + xv.w * wv3.w;
      }
    }
  }
  // z = relu(acc) -> LDS
  #pragma unroll
  for (int t = 0; t < TM; ++t) {
    float4 z = make_float4(fmaxf(acc[t][0], 0.f), fmaxf(acc[t][1], 0.f),
                           fmaxf(acc[t][2], 0.f), fmaxf(acc[t][3], 0.f));
    *(float4*)&zl[(nodeg * TM + t) * WP + 4 * colq] = z;
  }
  __syncthreads();
  // restage Wl with W2 (64x64)
  for (int idx = tid; idx < 64 * 64; idx += 256) {
    int j = idx >> 6, kk = idx & 63;
    Wl[kk * WP + j] = W2p[idx];
  }
  __syncthreads();
  const float4 b2v = *(const float4*)&b2p[4 * colq];
  float acc2[TM][4];
  #pragma unroll
  for (int t = 0; t < TM; ++t) {
    acc2[t][0] = b2v.x; acc2[t][1] = b2v.y; acc2[t][2] = b2v.z; acc2[t][3] = b2v.w;
  }
  for (int k2 = 0; k2 < 64; k2 += 4) {
    const float4 wv0 = *(const float4*)&Wl[(k2 + 0) * WP + 4 * colq];
    const float4 wv1 = *(const float4*)&Wl[(k2 + 1) * WP + 4 * colq];
    const float4 wv2 = *(const float4*)&Wl[(k2 + 2) * WP + 4 * colq];
    const float4 wv3 = *(const float4*)&Wl[(k2 + 3) * WP + 4 * colq];
    #pragma unroll
    for (int t = 0; t < TM; ++t) {
      const float4 xv = *(const float4*)&zl[(nodeg * TM + t) * WP + k2];
      acc2[t][0] += xv.x * wv0.x + xv.y * wv1.x + xv.z * wv2.x + xv.w * wv3.x;
      acc2[t][1] += xv.x * wv0.y + xv.y * wv1.y + xv.z * wv2.y + xv.w * wv3.y;
      acc2[t][2] += xv.x * wv0.z + xv.y * wv1.z + xv.z * wv2.z + xv.w * wv3.z;
      acc2[t][3] += xv.x * wv0.w + xv.y * wv1.w + xv.z * wv2.w + xv.w * wv3.w;
    }
  }
  #pragma unroll
  for (int t = 0; t < TM; ++t) {
    int n = nb + nodeg * TM + t;
    if (n < N) {
      *(float4*)&outp[(size_t)n * M + 4 * colq] =
          make_float4(acc2[t][0], acc2[t][1], acc2[t][2], acc2[t][3]);
    }
  }
}

// ---------------- launch ----------------
extern "C" void kernel_launch(void* const* d_in, const int* in_sizes, int n_in,
                              void* d_out, int out_size, void* d_ws, size_t ws_size,
                              hipStream_t stream) {
  (void)in_sizes; (void)n_in; (void)out_size; (void)ws_size;
  const float* x_stream  = (const float*)d_in[0];
  const float* x_device  = (const float*)d_in[1];
  const int*   edge_sd   = (const int*)d_in[2];
  const int*   edge_ds   = (const int*)d_in[3];
  const float* lstm_W_ih = (const float*)d_in[4];
  const float* lstm_b_ih = (const float*)d_in[5];
  const float* lstm_b_hh = (const float*)d_in[6];
  const float* sc_W      = (const float*)d_in[7];
  const float* sc_b      = (const float*)d_in[8];
  const float* dev_W     = (const float*)d_in[9];
  const float* dev_b     = (const float*)d_in[10];
  const float* proj_W    = (const float*)d_in[11];
  const float* proj_b    = (const float*)d_in[12];
  const float* att_src   = (const float*)d_in[13];
  const float* att_dst   = (const float*)d_in[14];
  // d_in[15..17] = q, k_W, k_b — mathematically unused (softmax over singleton stack)
  const float* outp_W1   = (const float*)d_in[18];
  const float* outp_b1   = (const float*)d_in[19];
  const float* outp_W2   = (const float*)d_in[20];
  const float* outp_b2   = (const float*)d_in[21];
  float* out_f = (float*)d_out;

  float* ws = (float*)d_ws;
  size_t off = 0;
  float* h0  = ws + off; off += (size_t)NS_N * 128;
  float* h1  = ws + off; off += (size_t)ND_N * 128;
  unsigned short* xb0 = (unsigned short*)(ws + off); off += (size_t)NS_N * 64;  // bf16 128/node
  unsigned short* xb1 = (unsigned short*)(ws + off); off += (size_t)ND_N * 64;
  float* as0 = ws + off; off += (size_t)NS_N * 8;
  float* ad0 = ws + off; off += (size_t)NS_N * 8;
  float* as1 = ws + off; off += (size_t)ND_N * 8;
  float* ad1 = ws + off; off += (size_t)ND_N * 8;
  int* ip = (int*)(ws + off);
  int* cnt    = ip; ip += ND_N + NS_N;       // [cnt_sd | cnt_ds]  (zeroed)
  int* totals = ip; ip += 2;                 // (zeroed, contiguous with cnt)
  int* rp     = ip; ip += ND_N + NS_N;       // [rp_sd | rp_ds]
  int* cur    = ip; ip += ND_N + NS_N;       // fill cursors
  int* csr_sd = ip; ip += E_N;
  int* csr_ds = ip; ip += E_N;

  hipMemsetAsync(cnt, 0, (size_t)(ND_N + NS_N + 2) * sizeof(int), stream);

  const int EB = (E_N + 255) / 256;
  count2_kernel<<<EB, 256, 0, stream>>>(edge_sd + E_N, edge_ds + E_N, cnt, E_N);
  alloc_kernel<<<dim3((50000 + 255) / 256, 2), 256, 0, stream>>>(cnt, rp, cur, totals, 50000);
  fill2_kernel<<<dim3(EB, 2), 256, 0, stream>>>(edge_sd, edge_ds, cur, csr_sd, csr_ds, E_N);

  const int GB64 = (NS_N + 63) / 64;    // 782

  enc_fused_kernel<<<dim3(GB64, 2), 256, 0, stream>>>(
      x_stream, lstm_W_ih, lstm_b_ih, lstm_b_hh, sc_W, sc_b, h0,
      x_device, dev_W, dev_b, h1, NS_N);

  for (int l = 0; l < 2; ++l) {
    // dual projection + fused attention scores; output bf16 gather payload
    dense6_kernel<128, 128, 64, false, true, true><<<dim3(GB64, 2), 256, 0, stream>>>(
        h0, proj_W + (size_t)(l * 2 + 0) * 16384, proj_b + (l * 2 + 0) * 128, xb0,
        att_src + (l * 2 + 0) * 128, att_dst + (l * 2 + 1) * 128, as0, ad0,
        h1, proj_W + (size_t)(l * 2 + 1) * 16384, proj_b + (l * 2 + 1) * 128, xb1,
        att_src + (l * 2 + 1) * 128, att_dst + (l * 2 + 0) * 128, as1, ad1, NS_N);
    // fused aggregation for both edge types (bf16 gather)
    att_agg5_kernel<<<dim3((ND_N + 3) / 4, 2), 256, 0, stream>>>(
        rp, cnt, csr_sd, as0, ad1, xb0, h1,
        rp + 50000, cnt + 50000, csr_ds, as1, ad0, xb1, h0, ND_N);
  }

  // fused output heads (both types)
  headmlp_kernel<<<dim3(GB64, 2), 256, 0, stream>>>(
      h0, h1, outp_W1, outp_b1, outp_W2, outp_b2, out_f, NS_N);
}